// Round 5
// baseline (5364.220 us; speedup 1.0000x reference)
//
#include <hip/hip_runtime.h>
#include <math.h>

#define NC 2000
#define NP 1500
#define NA 40
#define LP 512
#define BSZ 4096

typedef _Float16 h2 __attribute__((ext_vector_type(2)));

// ======================= GNN (fused per compound) =======================
__global__ __launch_bounds__(320) void gnn_kernel(
    const int* __restrict__ compounds, const float* __restrict__ adjacencies,
    const float* __restrict__ embed_fp, const float* __restrict__ W_gnn,
    const float* __restrict__ b_gnn, float* __restrict__ comp_int)
{
    __shared__ float xs[40][68];
    __shared__ float hs[40][68];
    __shared__ float Ws[64][64];
    __shared__ float adjS[40][41];
    __shared__ float bS[64];
    const int n = blockIdx.x;
    const int tid = threadIdx.x;
    const int a = tid >> 3, g = tid & 7, cb = g * 8;

    for (int j = tid; j < 40 * 64; j += 320) {
        int r = j >> 6, c = j & 63;
        xs[r][c] = embed_fp[(size_t)compounds[n * NA + r] * 64 + c];
    }
    for (int j = tid; j < NA * NA; j += 320)
        adjS[j / NA][j % NA] = adjacencies[(size_t)n * (NA * NA) + j];

    for (int l = 0; l < 3; ++l) {
        __syncthreads();
        for (int j = tid; j < 4096; j += 320) Ws[j >> 6][j & 63] = W_gnn[l * 4096 + j];
        if (tid < 64) bS[tid] = b_gnn[l * 64 + tid];
        __syncthreads();
        float acc[8];
        #pragma unroll
        for (int j = 0; j < 8; ++j) acc[j] = bS[cb + j];
        #pragma unroll 8
        for (int d = 0; d < 64; ++d) {
            float x = xs[a][d];
            float4 w0 = *(const float4*)&Ws[d][cb];
            float4 w1 = *(const float4*)&Ws[d][cb + 4];
            acc[0] += x * w0.x; acc[1] += x * w0.y; acc[2] += x * w0.z; acc[3] += x * w0.w;
            acc[4] += x * w1.x; acc[5] += x * w1.y; acc[6] += x * w1.z; acc[7] += x * w1.w;
        }
        #pragma unroll
        for (int j = 0; j < 8; ++j) hs[a][cb + j] = fmaxf(acc[j], 0.f);
        __syncthreads();
        float4 x0 = *(float4*)&xs[a][cb];
        float4 x1 = *(float4*)&xs[a][cb + 4];
        #pragma unroll 8
        for (int b = 0; b < NA; ++b) {
            float ad = adjS[a][b];
            float4 h0 = *(const float4*)&hs[b][cb];
            float4 h1 = *(const float4*)&hs[b][cb + 4];
            x0.x += ad * h0.x; x0.y += ad * h0.y; x0.z += ad * h0.z; x0.w += ad * h0.w;
            x1.x += ad * h1.x; x1.y += ad * h1.y; x1.z += ad * h1.z; x1.w += ad * h1.w;
        }
        *(float4*)&xs[a][cb] = x0;
        *(float4*)&xs[a][cb + 4] = x1;
    }
    __syncthreads();
    if (tid < 64) {
        float s = 0.f;
        for (int r = 0; r < NA; ++r) s += xs[r][tid];
        comp_int[n * 64 + tid] = s * (1.0f / 40.0f);
    }
}

// ======================= CNN (fused 3-layer, fp16 dot2, 32-row tiles) =======================
// Layout per row: 75 dwords = E[0..37] (even pairs (x[2k],x[2k+1])) + O[38..74]
// (odd pairs (x[2k+1],x[2k+2])). Image cols live at padded cols pc=5..68 of 76;
// pads are zero. Kernel padded to 12 taps (K[11]=0) -> 6 half2 pairs.
#define TROWS 32
#define CBROWS 66       // rows 0..61 valid data; 62..65 overshoot (read-only, discarded)
#define RSTRIDE 75      // dwords per row

__device__ __forceinline__ void cnn_write_h(_Float16* hy, int row, int pc, _Float16 v)
{
    hy[(row * RSTRIDE + (pc >> 1)) * 2 + (pc & 1)] = v;
    hy[(row * RSTRIDE + 38 + ((pc - 1) >> 1)) * 2 + (1 - (pc & 1))] = v;
}

__device__ __forceinline__ void conv_pass_h2(
    const h2* __restrict__ X, h2* __restrict__ Y,
    const h2 (*__restrict__ kh)[6], float bias,
    int i0, int i1, int t0, int tid)
{
    const int c = tid & 63, rg = tid >> 6;
    const int colbase = (c & 1) ? (38 + ((c - 1) >> 1)) : (c >> 1);
    const int pc = c + 5;
    _Float16* hy = (_Float16*)Y;
    for (int rbase = i0 + rg * 8; rbase < i1; rbase += 32) {
        float acc[8];
        #pragma unroll
        for (int j = 0; j < 8; ++j) acc[j] = bias;
        #pragma unroll
        for (int i = 0; i < 6; ++i) {
            h2 s[18];
            #pragma unroll
            for (int t = 0; t < 18; ++t)
                s[t] = X[(rbase - 5 + t) * RSTRIDE + colbase + i];
            #pragma unroll
            for (int dr = 0; dr < 11; ++dr) {
                h2 kv = kh[dr][i];
                #pragma unroll
                for (int j = 0; j < 8; ++j)
                    acc[j] = __builtin_amdgcn_fdot2(s[dr + j], kv, acc[j], false);
            }
        }
        #pragma unroll
        for (int j = 0; j < 8; ++j) {
            int i = rbase + j;
            if (i < i1) {
                int gr = t0 - 15 + i;
                _Float16 v = (_Float16)((gr >= 0 && gr < LP) ? fmaxf(acc[j], 0.f) : 0.f);
                cnn_write_h(hy, i, pc, v);
            }
        }
    }
}

__global__ __launch_bounds__(256, 4) void cnn_kernel(
    const int* __restrict__ proteins, const float* __restrict__ embed_word,
    const float* __restrict__ K_cnn, const float* __restrict__ b_cnn,
    float* __restrict__ prot_part)
{
    __shared__ h2 bufA[CBROWS * RSTRIDE];
    __shared__ h2 bufB[CBROWS * RSTRIDE];
    __shared__ h2 kh[3][11][6];
    const int tile = blockIdx.x, p = blockIdx.y;
    const int t0 = tile * TROWS, tid = threadIdx.x;

    // zero both buffers (pads, boundary rows, overshoot)
    for (int j = tid; j < CBROWS * RSTRIDE; j += 256) {
        ((unsigned*)bufA)[j] = 0u;
        ((unsigned*)bufB)[j] = 0u;
    }
    // kernel taps as half2 pairs, 12-tap padded
    if (tid < 198) {
        int l = tid / 66, r = tid % 66, dr = r / 6, i2 = r % 6;
        float lo = K_cnn[l * 121 + dr * 11 + i2 * 2];
        float hi = (i2 * 2 + 1 < 11) ? K_cnn[l * 121 + dr * 11 + i2 * 2 + 1] : 0.f;
        h2 kv; kv.x = (_Float16)lo; kv.y = (_Float16)hi;
        kh[l][dr][i2] = kv;
    }
    __syncthreads();
    // layer-0 input: rows 0..61 (gr = t0-15+i), cols 0..63
    {
        _Float16* hA = (_Float16*)bufA;
        for (int j = tid; j < 62 * 64; j += 256) {
            int i = j >> 6, cc = j & 63, gr = t0 - 15 + i;
            if (gr >= 0 && gr < LP) {
                _Float16 v = (_Float16)embed_word[(size_t)proteins[p * LP + gr] * 64 + cc];
                cnn_write_h(hA, i, cc + 5, v);
            }
        }
    }
    __syncthreads();
    conv_pass_h2(bufA, bufB, kh[0], b_cnn[0], 5, 57, t0, tid);   // L1: rows [t0-10, t0+42)
    __syncthreads();
    conv_pass_h2(bufB, bufA, kh[1], b_cnn[1], 10, 52, t0, tid);  // L2: rows [t0-5, t0+37)
    __syncthreads();

    // L3: rows [15,47) -> column sums (exactly one rbase iter per row-group)
    const int c = tid & 63, rg = tid >> 6;
    const int colbase = (c & 1) ? (38 + ((c - 1) >> 1)) : (c >> 1);
    float csum = 0.f;
    {
        const float bias2 = b_cnn[2];
        const int rbase = 15 + rg * 8;
        float acc[8];
        #pragma unroll
        for (int j = 0; j < 8; ++j) acc[j] = bias2;
        #pragma unroll
        for (int i = 0; i < 6; ++i) {
            h2 s[18];
            #pragma unroll
            for (int t = 0; t < 18; ++t)
                s[t] = bufA[(rbase - 5 + t) * RSTRIDE + colbase + i];
            #pragma unroll
            for (int dr = 0; dr < 11; ++dr) {
                h2 kv = kh[2][dr][i];
                #pragma unroll
                for (int j = 0; j < 8; ++j)
                    acc[j] = __builtin_amdgcn_fdot2(s[dr + j], kv, acc[j], false);
            }
        }
        #pragma unroll
        for (int j = 0; j < 8; ++j) csum += fmaxf(acc[j], 0.f);
    }
    // reduce: alias red onto bufB (free after L2)
    float* red = (float*)bufB;
    red[rg * 64 + c] = csum;
    __syncthreads();
    if (tid < 64)
        prot_part[((size_t)p * 16 + tile) * 64 + tid] =
            red[0 * 64 + tid] + red[1 * 64 + tid] + red[2 * 64 + tid] + red[3 * 64 + tid];
}

__global__ void cnn_reduce(const float* __restrict__ prot_part, float* __restrict__ prot_int)
{
    const int p = blockIdx.x, c = threadIdx.x;
    float s = 0.f;
    for (int t = 0; t < 16; ++t) s += prot_part[((size_t)p * 16 + t) * 64 + c];
    prot_int[p * 64 + c] = s * (1.0f / 512.0f);
}

// ======================= GCN: split-K GEMM (N=64) + epilogue =======================
__global__ __launch_bounds__(256) void spk_gemm64(
    const float* __restrict__ A, const float* __restrict__ X,
    float* __restrict__ part, int M, int kchunk)
{
    __shared__ float As[64][17];
    __shared__ float Xs[16][64];
    const int rb = blockIdx.x * 64;
    const int s = blockIdx.y;
    const int k0 = s * kchunk;
    const int k1 = (k0 + kchunk < M) ? (k0 + kchunk) : M;
    const int tid = threadIdx.x, tx = tid & 15, ty = tid >> 4;
    float acc[4][4] = {};
    for (int kb = k0; kb < k1; kb += 16) {
        #pragma unroll
        for (int q = 0; q < 4; ++q) {
            int r = (tid >> 4) + q * 16, kc = tid & 15;
            int row = rb + r, kidx = kb + kc;
            As[r][kc] = (row < M && kidx < k1) ? A[(size_t)row * M + kidx] : 0.f;
        }
        #pragma unroll
        for (int q = 0; q < 4; ++q) {
            int kr = (tid >> 6) + q * 4, cc = tid & 63;
            int kidx = kb + kr;
            Xs[kr][cc] = (kidx < k1) ? X[(size_t)kidx * 64 + cc] : 0.f;
        }
        __syncthreads();
        #pragma unroll
        for (int kk = 0; kk < 16; ++kk) {
            float a0 = As[ty * 4 + 0][kk], a1 = As[ty * 4 + 1][kk];
            float a2 = As[ty * 4 + 2][kk], a3 = As[ty * 4 + 3][kk];
            float4 b4 = *(const float4*)&Xs[kk][tx * 4];
            acc[0][0] += a0 * b4.x; acc[0][1] += a0 * b4.y; acc[0][2] += a0 * b4.z; acc[0][3] += a0 * b4.w;
            acc[1][0] += a1 * b4.x; acc[1][1] += a1 * b4.y; acc[1][2] += a1 * b4.z; acc[1][3] += a1 * b4.w;
            acc[2][0] += a2 * b4.x; acc[2][1] += a2 * b4.y; acc[2][2] += a2 * b4.z; acc[2][3] += a2 * b4.w;
            acc[3][0] += a3 * b4.x; acc[3][1] += a3 * b4.y; acc[3][2] += a3 * b4.z; acc[3][3] += a3 * b4.w;
        }
        __syncthreads();
    }
    #pragma unroll
    for (int i = 0; i < 4; ++i) {
        int row = rb + ty * 4 + i;
        if (row < M)
            *(float4*)&part[((size_t)s * M + row) * 64 + tx * 4] =
                make_float4(acc[i][0], acc[i][1], acc[i][2], acc[i][3]);
    }
}

__global__ __launch_bounds__(256) void gcn_epi(
    const float* __restrict__ part, int S, int M,
    const float* __restrict__ W, const float* __restrict__ bias,
    float* __restrict__ Xout)
{
    __shared__ float Ys[64][68];
    __shared__ float Ws[64][64];
    const int rb = blockIdx.x * 64;
    const int tid = threadIdx.x;
    for (int j = tid; j < 4096; j += 256) Ws[j >> 6][j & 63] = W[j];
    for (int j = tid; j < 4096; j += 256) {
        int r = j >> 6, c = j & 63;
        float sum = 0.f;
        if (rb + r < M)
            for (int t = 0; t < S; ++t) sum += part[((size_t)t * M + rb + r) * 64 + c];
        Ys[r][c] = sum;
    }
    __syncthreads();
    const int tx = tid & 15, ty = tid >> 4;
    float acc[4][4];
    #pragma unroll
    for (int i = 0; i < 4; ++i)
        #pragma unroll
        for (int j = 0; j < 4; ++j) acc[i][j] = bias[tx * 4 + j];
    for (int d = 0; d < 64; ++d) {
        float a0 = Ys[ty * 4 + 0][d], a1 = Ys[ty * 4 + 1][d];
        float a2 = Ys[ty * 4 + 2][d], a3 = Ys[ty * 4 + 3][d];
        float4 w4 = *(const float4*)&Ws[d][tx * 4];
        acc[0][0] += a0 * w4.x; acc[0][1] += a0 * w4.y; acc[0][2] += a0 * w4.z; acc[0][3] += a0 * w4.w;
        acc[1][0] += a1 * w4.x; acc[1][1] += a1 * w4.y; acc[1][2] += a1 * w4.z; acc[1][3] += a1 * w4.w;
        acc[2][0] += a2 * w4.x; acc[2][1] += a2 * w4.y; acc[2][2] += a2 * w4.z; acc[2][3] += a2 * w4.w;
        acc[3][0] += a3 * w4.x; acc[3][1] += a3 * w4.y; acc[3][2] += a3 * w4.z; acc[3][3] += a3 * w4.w;
    }
    #pragma unroll
    for (int i = 0; i < 4; ++i) {
        int row = rb + ty * 4 + i;
        if (row < M)
            #pragma unroll
            for (int j = 0; j < 4; ++j)
                Xout[(size_t)row * 64 + tx * 4 + j] = fmaxf(acc[i][j], 0.f);
    }
}

// ======================= generic GEMM + bias + relu (opt. row gather) =======================
template<bool GATHER>
__global__ __launch_bounds__(256) void gemm_bias_relu(
    const float* __restrict__ A, int lda, const int* __restrict__ idx,
    const float* __restrict__ Bm, const float* __restrict__ bias,
    float* __restrict__ C, int M, int N, int K)
{
    __shared__ float As[64][17];
    __shared__ float Bs[16][64];
    const int rb = blockIdx.x * 64, nb = blockIdx.y * 64;
    const int tid = threadIdx.x, tx = tid & 15, ty = tid >> 4;
    float acc[4][4] = {};
    for (int kb = 0; kb < K; kb += 16) {
        #pragma unroll
        for (int q = 0; q < 4; ++q) {
            int r = (tid >> 4) + q * 16, kc = tid & 15;
            int row = rb + r;
            float v = 0.f;
            if (row < M) {
                size_t ar = GATHER ? (size_t)idx[row] : (size_t)row;
                v = A[ar * lda + kb + kc];
            }
            As[r][kc] = v;
        }
        #pragma unroll
        for (int q = 0; q < 4; ++q) {
            int kr = (tid >> 6) + q * 4, cc = tid & 63;
            Bs[kr][cc] = Bm[(size_t)(kb + kr) * N + nb + cc];
        }
        __syncthreads();
        #pragma unroll
        for (int kk = 0; kk < 16; ++kk) {
            float a0 = As[ty * 4 + 0][kk], a1 = As[ty * 4 + 1][kk];
            float a2 = As[ty * 4 + 2][kk], a3 = As[ty * 4 + 3][kk];
            float4 b4 = *(const float4*)&Bs[kk][tx * 4];
            acc[0][0] += a0 * b4.x; acc[0][1] += a0 * b4.y; acc[0][2] += a0 * b4.z; acc[0][3] += a0 * b4.w;
            acc[1][0] += a1 * b4.x; acc[1][1] += a1 * b4.y; acc[1][2] += a1 * b4.z; acc[1][3] += a1 * b4.w;
            acc[2][0] += a2 * b4.x; acc[2][1] += a2 * b4.y; acc[2][2] += a2 * b4.z; acc[2][3] += a2 * b4.w;
            acc[3][0] += a3 * b4.x; acc[3][1] += a3 * b4.y; acc[3][2] += a3 * b4.z; acc[3][3] += a3 * b4.w;
        }
        __syncthreads();
    }
    #pragma unroll
    for (int i = 0; i < 4; ++i) {
        int row = rb + ty * 4 + i;
        if (row < M)
            #pragma unroll
            for (int j = 0; j < 4; ++j) {
                int col = nb + tx * 4 + j;
                C[(size_t)row * N + col] = fmaxf(acc[i][j] + bias[col], 0.f);
            }
    }
}

// ======================= concat + final head =======================
__global__ void concat_kernel(
    const int* __restrict__ idx_c, const int* __restrict__ idx_p,
    const float* __restrict__ comp_int, const float* __restrict__ Xc,
    const float* __restrict__ fd3, const float* __restrict__ prot_int,
    const float* __restrict__ Xp, const float* __restrict__ fp3,
    float* __restrict__ cat)
{
    int j = blockIdx.x * 256 + threadIdx.x;
    if (j >= BSZ * 384) return;
    int r = j / 384, c = j % 384;
    float v;
    if (c < 64)       v = comp_int[(size_t)idx_c[r] * 64 + c];
    else if (c < 128) v = Xc[(size_t)idx_c[r] * 64 + (c - 64)];
    else if (c < 192) v = fd3[(size_t)r * 64 + (c - 128)];
    else if (c < 256) v = prot_int[(size_t)idx_p[r] * 64 + (c - 192)];
    else if (c < 320) v = Xp[(size_t)idx_p[r] * 64 + (c - 256)];
    else              v = fp3[(size_t)r * 64 + (c - 320)];
    cat[j] = v;
}

__global__ void head_final(
    const float* __restrict__ h3, const float* __restrict__ W_int,
    const float* __restrict__ b_int, float* __restrict__ out)
{
    int r = blockIdx.x * 256 + threadIdx.x;
    if (r >= BSZ) return;
    float s0 = b_int[0], s1 = b_int[1];
    for (int k = 0; k < 256; ++k) {
        float h = h3[(size_t)r * 256 + k];
        s0 += h * W_int[k * 2 + 0];
        s1 += h * W_int[k * 2 + 1];
    }
    out[r * 2 + 0] = 1.f / (1.f + expf(-s0));
    out[r * 2 + 1] = 1.f / (1.f + expf(-s1));
}

// ======================= launch =======================
extern "C" void kernel_launch(void* const* d_in, const int* in_sizes, int n_in,
                              void* d_out, int out_size, void* d_ws, size_t ws_size,
                              hipStream_t stream)
{
    const int*   idx_c        = (const int*)  d_in[0];
    const int*   idx_p        = (const int*)  d_in[1];
    const int*   compounds    = (const int*)  d_in[2];
    const int*   proteins     = (const int*)  d_in[3];
    const float* adjacencies  = (const float*)d_in[4];
    const float* A_c          = (const float*)d_in[5];
    const float* A_p          = (const float*)d_in[6];
    const float* embed_fp     = (const float*)d_in[7];
    const float* embed_word   = (const float*)d_in[8];
    const float* Xs_c         = (const float*)d_in[9];
    const float* Xs_p         = (const float*)d_in[10];
    const float* drug_feat    = (const float*)d_in[11];
    const float* protein_feat = (const float*)d_in[12];
    const float* W_gnn        = (const float*)d_in[13];
    const float* b_gnn        = (const float*)d_in[14];
    const float* K_cnn        = (const float*)d_in[15];
    const float* b_cnn        = (const float*)d_in[16];
    const float* W_gcn_d      = (const float*)d_in[17];
    const float* b_gcn_d      = (const float*)d_in[18];
    const float* W_gcn_p      = (const float*)d_in[19];
    const float* b_gcn_p      = (const float*)d_in[20];
    const float* Wd1 = (const float*)d_in[21]; const float* bd1 = (const float*)d_in[22];
    const float* Wd2 = (const float*)d_in[23]; const float* bd2 = (const float*)d_in[24];
    const float* Wd3 = (const float*)d_in[25]; const float* bd3 = (const float*)d_in[26];
    const float* Wp1 = (const float*)d_in[27]; const float* bp1 = (const float*)d_in[28];
    const float* Wp2 = (const float*)d_in[29]; const float* bp2 = (const float*)d_in[30];
    const float* Wp3 = (const float*)d_in[31]; const float* bp3 = (const float*)d_in[32];
    const float* Wo1 = (const float*)d_in[33]; const float* bo1 = (const float*)d_in[34];
    const float* Wo2 = (const float*)d_in[35]; const float* bo2 = (const float*)d_in[36];
    const float* Wo3 = (const float*)d_in[37]; const float* bo3 = (const float*)d_in[38];
    const float* W_int = (const float*)d_in[39]; const float* b_int = (const float*)d_in[40];

    float* ws = (float*)d_ws;
    float* comp_int  = ws; ws += NC * 64;
    float* prot_part = ws; ws += NP * 16 * 64;
    float* prot_int  = ws; ws += NP * 64;
    float* gcn_part  = ws; ws += 8 * NC * 64;
    float* Xc_a = ws; ws += NC * 64;
    float* Xc_b = ws; ws += NC * 64;
    float* Xp_a = ws; ws += NP * 64;
    float* Xp_b = ws; ws += NP * 64;
    float* fd1 = ws; ws += BSZ * 128;
    float* fd2 = ws; ws += BSZ * 64;
    float* fd3 = ws; ws += BSZ * 64;
    float* fp1 = ws; ws += BSZ * 128;
    float* fp2 = ws; ws += BSZ * 64;
    float* fp3 = ws; ws += BSZ * 64;
    float* cat = ws; ws += BSZ * 384;
    float* h1  = ws; ws += BSZ * 256;
    float* h2m = ws; ws += BSZ * 256;
    float* h3  = ws; ws += BSZ * 256;
    (void)ws_size; (void)in_sizes; (void)n_in; (void)out_size;

    // branch 1: compound GNN
    gnn_kernel<<<NC, 320, 0, stream>>>(compounds, adjacencies, embed_fp, W_gnn, b_gnn, comp_int);
    // branch 2: protein CNN (fp16 dot2, 32-row tiles)
    cnn_kernel<<<dim3(16, NP), 256, 0, stream>>>(proteins, embed_word, K_cnn, b_cnn, prot_part);
    cnn_reduce<<<NP, 64, 0, stream>>>(prot_part, prot_int);
    // branch 3: GCN drug
    spk_gemm64<<<dim3(32, 8), 256, 0, stream>>>(A_c, Xs_c, gcn_part, NC, 256);
    gcn_epi<<<32, 256, 0, stream>>>(gcn_part, 8, NC, W_gcn_d, b_gcn_d, Xc_a);
    spk_gemm64<<<dim3(32, 8), 256, 0, stream>>>(A_c, Xc_a, gcn_part, NC, 256);
    gcn_epi<<<32, 256, 0, stream>>>(gcn_part, 8, NC, W_gcn_d + 4096, b_gcn_d + 64, Xc_b);
    // branch 3b: GCN protein
    spk_gemm64<<<dim3(24, 8), 256, 0, stream>>>(A_p, Xs_p, gcn_part, NP, 192);
    gcn_epi<<<24, 256, 0, stream>>>(gcn_part, 8, NP, W_gcn_p, b_gcn_p, Xp_a);
    spk_gemm64<<<dim3(24, 8), 256, 0, stream>>>(A_p, Xp_a, gcn_part, NP, 192);
    gcn_epi<<<24, 256, 0, stream>>>(gcn_part, 8, NP, W_gcn_p + 4096, b_gcn_p + 64, Xp_b);
    // branch 4: drug MLP
    gemm_bias_relu<true ><<<dim3(64, 2), 256, 0, stream>>>(drug_feat, 1024, idx_c, Wd1, bd1, fd1, BSZ, 128, 1024);
    gemm_bias_relu<false><<<dim3(64, 1), 256, 0, stream>>>(fd1, 128, nullptr, Wd2, bd2, fd2, BSZ, 64, 128);
    gemm_bias_relu<false><<<dim3(64, 1), 256, 0, stream>>>(fd2, 64, nullptr, Wd3, bd3, fd3, BSZ, 64, 64);
    // branch 5: protein MLP
    gemm_bias_relu<true ><<<dim3(64, 2), 256, 0, stream>>>(protein_feat, 1024, idx_p, Wp1, bp1, fp1, BSZ, 128, 1024);
    gemm_bias_relu<false><<<dim3(64, 1), 256, 0, stream>>>(fp1, 128, nullptr, Wp2, bp2, fp2, BSZ, 64, 128);
    gemm_bias_relu<false><<<dim3(64, 1), 256, 0, stream>>>(fp2, 64, nullptr, Wp3, bp3, fp3, BSZ, 64, 64);
    // head
    concat_kernel<<<(BSZ * 384 + 255) / 256, 256, 0, stream>>>(idx_c, idx_p, comp_int, Xc_b, fd3, prot_int, Xp_b, fp3, cat);
    gemm_bias_relu<false><<<dim3(64, 4), 256, 0, stream>>>(cat, 384, nullptr, Wo1, bo1, h1, BSZ, 256, 384);
    gemm_bias_relu<false><<<dim3(64, 4), 256, 0, stream>>>(h1, 256, nullptr, Wo2, bo2, h2m, BSZ, 256, 256);
    gemm_bias_relu<false><<<dim3(64, 4), 256, 0, stream>>>(h2m, 256, nullptr, Wo3, bo3, h3, BSZ, 256, 256);
    head_final<<<(BSZ + 255) / 256, 256, 0, stream>>>(h3, W_int, b_int, (float*)d_out);
}

// Round 6
// 1602.670 us; speedup vs baseline: 3.3471x; 3.3471x over previous
//
#include <hip/hip_runtime.h>
#include <math.h>

#define NC 2000
#define NP 1500
#define NA 40
#define LP 512
#define BSZ 4096

typedef _Float16 h2 __attribute__((ext_vector_type(2)));

// ======================= GNN (fused per compound) =======================
__global__ __launch_bounds__(320) void gnn_kernel(
    const int* __restrict__ compounds, const float* __restrict__ adjacencies,
    const float* __restrict__ embed_fp, const float* __restrict__ W_gnn,
    const float* __restrict__ b_gnn, float* __restrict__ comp_int)
{
    __shared__ float xs[40][68];
    __shared__ float hs[40][68];
    __shared__ float Ws[64][64];
    __shared__ float adjS[40][41];
    __shared__ float bS[64];
    const int n = blockIdx.x;
    const int tid = threadIdx.x;
    const int a = tid >> 3, g = tid & 7, cb = g * 8;

    for (int j = tid; j < 40 * 64; j += 320) {
        int r = j >> 6, c = j & 63;
        xs[r][c] = embed_fp[(size_t)compounds[n * NA + r] * 64 + c];
    }
    for (int j = tid; j < NA * NA; j += 320)
        adjS[j / NA][j % NA] = adjacencies[(size_t)n * (NA * NA) + j];

    for (int l = 0; l < 3; ++l) {
        __syncthreads();
        for (int j = tid; j < 4096; j += 320) Ws[j >> 6][j & 63] = W_gnn[l * 4096 + j];
        if (tid < 64) bS[tid] = b_gnn[l * 64 + tid];
        __syncthreads();
        float acc[8];
        #pragma unroll
        for (int j = 0; j < 8; ++j) acc[j] = bS[cb + j];
        #pragma unroll 8
        for (int d = 0; d < 64; ++d) {
            float x = xs[a][d];
            float4 w0 = *(const float4*)&Ws[d][cb];
            float4 w1 = *(const float4*)&Ws[d][cb + 4];
            acc[0] += x * w0.x; acc[1] += x * w0.y; acc[2] += x * w0.z; acc[3] += x * w0.w;
            acc[4] += x * w1.x; acc[5] += x * w1.y; acc[6] += x * w1.z; acc[7] += x * w1.w;
        }
        #pragma unroll
        for (int j = 0; j < 8; ++j) hs[a][cb + j] = fmaxf(acc[j], 0.f);
        __syncthreads();
        float4 x0 = *(float4*)&xs[a][cb];
        float4 x1 = *(float4*)&xs[a][cb + 4];
        #pragma unroll 8
        for (int b = 0; b < NA; ++b) {
            float ad = adjS[a][b];
            float4 h0 = *(const float4*)&hs[b][cb];
            float4 h1 = *(const float4*)&hs[b][cb + 4];
            x0.x += ad * h0.x; x0.y += ad * h0.y; x0.z += ad * h0.z; x0.w += ad * h0.w;
            x1.x += ad * h1.x; x1.y += ad * h1.y; x1.z += ad * h1.z; x1.w += ad * h1.w;
        }
        *(float4*)&xs[a][cb] = x0;
        *(float4*)&xs[a][cb + 4] = x1;
    }
    __syncthreads();
    if (tid < 64) {
        float s = 0.f;
        for (int r = 0; r < NA; ++r) s += xs[r][tid];
        comp_int[n * 64 + tid] = s * (1.0f / 40.0f);
    }
}

// ======================= CNN (fused 3-layer, fp16 dot2, 32-row tiles) =======================
// Layout per row: 75 dwords = E[0..37] (even pairs (x[2k],x[2k+1])) + O[38..74]
// (odd pairs (x[2k+1],x[2k+2])). Image cols live at padded cols pc=5..68 of 76;
// pads are zero. Kernel padded to 12 taps (K[11]=0) -> 6 half2 pairs.
#define TROWS 32
#define CBROWS 66       // rows 0..61 valid data; 62..65 overshoot (read-only, discarded)
#define RSTRIDE 75      // dwords per row

__device__ __forceinline__ void cnn_write_h(_Float16* hy, int row, int pc, _Float16 v)
{
    hy[(row * RSTRIDE + (pc >> 1)) * 2 + (pc & 1)] = v;
    hy[(row * RSTRIDE + 38 + ((pc - 1) >> 1)) * 2 + (1 - (pc & 1))] = v;
}

__device__ __forceinline__ void conv_pass_h2(
    const h2* __restrict__ X, h2* __restrict__ Y,
    const h2 (*__restrict__ kh)[6], float bias,
    int i0, int i1, int t0, int tid)
{
    const int c = tid & 63, rg = tid >> 6;
    const int colbase = (c & 1) ? (38 + ((c - 1) >> 1)) : (c >> 1);
    const int pc = c + 5;
    _Float16* hy = (_Float16*)Y;
    for (int rbase = i0 + rg * 8; rbase < i1; rbase += 32) {
        float acc[8];
        #pragma unroll
        for (int j = 0; j < 8; ++j) acc[j] = bias;
        #pragma unroll
        for (int i = 0; i < 6; ++i) {
            h2 s[18];
            #pragma unroll
            for (int t = 0; t < 18; ++t)
                s[t] = X[(rbase - 5 + t) * RSTRIDE + colbase + i];
            #pragma unroll
            for (int dr = 0; dr < 11; ++dr) {
                h2 kv = kh[dr][i];
                #pragma unroll
                for (int j = 0; j < 8; ++j)
                    acc[j] = __builtin_amdgcn_fdot2(s[dr + j], kv, acc[j], false);
            }
        }
        #pragma unroll
        for (int j = 0; j < 8; ++j) {
            int i = rbase + j;
            if (i < i1) {
                int gr = t0 - 15 + i;
                _Float16 v = (_Float16)((gr >= 0 && gr < LP) ? fmaxf(acc[j], 0.f) : 0.f);
                cnn_write_h(hy, i, pc, v);
            }
        }
    }
}

__global__ __launch_bounds__(256) void cnn_kernel(
    const int* __restrict__ proteins, const float* __restrict__ embed_word,
    const float* __restrict__ K_cnn, const float* __restrict__ b_cnn,
    float* __restrict__ prot_part)
{
    __shared__ h2 bufA[CBROWS * RSTRIDE];
    __shared__ h2 bufB[CBROWS * RSTRIDE];
    __shared__ h2 kh[3][11][6];
    const int tile = blockIdx.x, p = blockIdx.y;
    const int t0 = tile * TROWS, tid = threadIdx.x;

    // zero both buffers (pads, boundary rows, overshoot)
    for (int j = tid; j < CBROWS * RSTRIDE; j += 256) {
        ((unsigned*)bufA)[j] = 0u;
        ((unsigned*)bufB)[j] = 0u;
    }
    // kernel taps as half2 pairs, 12-tap padded
    if (tid < 198) {
        int l = tid / 66, r = tid % 66, dr = r / 6, i2 = r % 6;
        float lo = K_cnn[l * 121 + dr * 11 + i2 * 2];
        float hi = (i2 * 2 + 1 < 11) ? K_cnn[l * 121 + dr * 11 + i2 * 2 + 1] : 0.f;
        h2 kv; kv.x = (_Float16)lo; kv.y = (_Float16)hi;
        kh[l][dr][i2] = kv;
    }
    __syncthreads();
    // layer-0 input: rows 0..61 (gr = t0-15+i), cols 0..63
    {
        _Float16* hA = (_Float16*)bufA;
        for (int j = tid; j < 62 * 64; j += 256) {
            int i = j >> 6, cc = j & 63, gr = t0 - 15 + i;
            if (gr >= 0 && gr < LP) {
                _Float16 v = (_Float16)embed_word[(size_t)proteins[p * LP + gr] * 64 + cc];
                cnn_write_h(hA, i, cc + 5, v);
            }
        }
    }
    __syncthreads();
    conv_pass_h2(bufA, bufB, kh[0], b_cnn[0], 5, 57, t0, tid);   // L1: rows [t0-10, t0+42)
    __syncthreads();
    conv_pass_h2(bufB, bufA, kh[1], b_cnn[1], 10, 52, t0, tid);  // L2: rows [t0-5, t0+37)
    __syncthreads();

    // L3: rows [15,47) -> column sums (exactly one rbase iter per row-group)
    const int c = tid & 63, rg = tid >> 6;
    const int colbase = (c & 1) ? (38 + ((c - 1) >> 1)) : (c >> 1);
    float csum = 0.f;
    {
        const float bias2 = b_cnn[2];
        const int rbase = 15 + rg * 8;
        float acc[8];
        #pragma unroll
        for (int j = 0; j < 8; ++j) acc[j] = bias2;
        #pragma unroll
        for (int i = 0; i < 6; ++i) {
            h2 s[18];
            #pragma unroll
            for (int t = 0; t < 18; ++t)
                s[t] = bufA[(rbase - 5 + t) * RSTRIDE + colbase + i];
            #pragma unroll
            for (int dr = 0; dr < 11; ++dr) {
                h2 kv = kh[2][dr][i];
                #pragma unroll
                for (int j = 0; j < 8; ++j)
                    acc[j] = __builtin_amdgcn_fdot2(s[dr + j], kv, acc[j], false);
            }
        }
        #pragma unroll
        for (int j = 0; j < 8; ++j) csum += fmaxf(acc[j], 0.f);
    }
    // reduce: alias red onto bufB (free after L2)
    float* red = (float*)bufB;
    red[rg * 64 + c] = csum;
    __syncthreads();
    if (tid < 64)
        prot_part[((size_t)p * 16 + tile) * 64 + tid] =
            red[0 * 64 + tid] + red[1 * 64 + tid] + red[2 * 64 + tid] + red[3 * 64 + tid];
}

__global__ void cnn_reduce(const float* __restrict__ prot_part, float* __restrict__ prot_int)
{
    const int p = blockIdx.x, c = threadIdx.x;
    float s = 0.f;
    for (int t = 0; t < 16; ++t) s += prot_part[((size_t)p * 16 + t) * 64 + c];
    prot_int[p * 64 + c] = s * (1.0f / 512.0f);
}

// ======================= GCN: split-K GEMM (N=64) + epilogue =======================
__global__ __launch_bounds__(256) void spk_gemm64(
    const float* __restrict__ A, const float* __restrict__ X,
    float* __restrict__ part, int M, int kchunk)
{
    __shared__ float As[64][17];
    __shared__ float Xs[16][64];
    const int rb = blockIdx.x * 64;
    const int s = blockIdx.y;
    const int k0 = s * kchunk;
    const int k1 = (k0 + kchunk < M) ? (k0 + kchunk) : M;
    const int tid = threadIdx.x, tx = tid & 15, ty = tid >> 4;
    float acc[4][4] = {};
    for (int kb = k0; kb < k1; kb += 16) {
        #pragma unroll
        for (int q = 0; q < 4; ++q) {
            int r = (tid >> 4) + q * 16, kc = tid & 15;
            int row = rb + r, kidx = kb + kc;
            As[r][kc] = (row < M && kidx < k1) ? A[(size_t)row * M + kidx] : 0.f;
        }
        #pragma unroll
        for (int q = 0; q < 4; ++q) {
            int kr = (tid >> 6) + q * 4, cc = tid & 63;
            int kidx = kb + kr;
            Xs[kr][cc] = (kidx < k1) ? X[(size_t)kidx * 64 + cc] : 0.f;
        }
        __syncthreads();
        #pragma unroll
        for (int kk = 0; kk < 16; ++kk) {
            float a0 = As[ty * 4 + 0][kk], a1 = As[ty * 4 + 1][kk];
            float a2 = As[ty * 4 + 2][kk], a3 = As[ty * 4 + 3][kk];
            float4 b4 = *(const float4*)&Xs[kk][tx * 4];
            acc[0][0] += a0 * b4.x; acc[0][1] += a0 * b4.y; acc[0][2] += a0 * b4.z; acc[0][3] += a0 * b4.w;
            acc[1][0] += a1 * b4.x; acc[1][1] += a1 * b4.y; acc[1][2] += a1 * b4.z; acc[1][3] += a1 * b4.w;
            acc[2][0] += a2 * b4.x; acc[2][1] += a2 * b4.y; acc[2][2] += a2 * b4.z; acc[2][3] += a2 * b4.w;
            acc[3][0] += a3 * b4.x; acc[3][1] += a3 * b4.y; acc[3][2] += a3 * b4.z; acc[3][3] += a3 * b4.w;
        }
        __syncthreads();
    }
    #pragma unroll
    for (int i = 0; i < 4; ++i) {
        int row = rb + ty * 4 + i;
        if (row < M)
            *(float4*)&part[((size_t)s * M + row) * 64 + tx * 4] =
                make_float4(acc[i][0], acc[i][1], acc[i][2], acc[i][3]);
    }
}

__global__ __launch_bounds__(256) void gcn_epi(
    const float* __restrict__ part, int S, int M,
    const float* __restrict__ W, const float* __restrict__ bias,
    float* __restrict__ Xout)
{
    __shared__ float Ys[64][68];
    __shared__ float Ws[64][64];
    const int rb = blockIdx.x * 64;
    const int tid = threadIdx.x;
    for (int j = tid; j < 4096; j += 256) Ws[j >> 6][j & 63] = W[j];
    for (int j = tid; j < 4096; j += 256) {
        int r = j >> 6, c = j & 63;
        float sum = 0.f;
        if (rb + r < M)
            for (int t = 0; t < S; ++t) sum += part[((size_t)t * M + rb + r) * 64 + c];
        Ys[r][c] = sum;
    }
    __syncthreads();
    const int tx = tid & 15, ty = tid >> 4;
    float acc[4][4];
    #pragma unroll
    for (int i = 0; i < 4; ++i)
        #pragma unroll
        for (int j = 0; j < 4; ++j) acc[i][j] = bias[tx * 4 + j];
    for (int d = 0; d < 64; ++d) {
        float a0 = Ys[ty * 4 + 0][d], a1 = Ys[ty * 4 + 1][d];
        float a2 = Ys[ty * 4 + 2][d], a3 = Ys[ty * 4 + 3][d];
        float4 w4 = *(const float4*)&Ws[d][tx * 4];
        acc[0][0] += a0 * w4.x; acc[0][1] += a0 * w4.y; acc[0][2] += a0 * w4.z; acc[0][3] += a0 * w4.w;
        acc[1][0] += a1 * w4.x; acc[1][1] += a1 * w4.y; acc[1][2] += a1 * w4.z; acc[1][3] += a1 * w4.w;
        acc[2][0] += a2 * w4.x; acc[2][1] += a2 * w4.y; acc[2][2] += a2 * w4.z; acc[2][3] += a2 * w4.w;
        acc[3][0] += a3 * w4.x; acc[3][1] += a3 * w4.y; acc[3][2] += a3 * w4.z; acc[3][3] += a3 * w4.w;
    }
    #pragma unroll
    for (int i = 0; i < 4; ++i) {
        int row = rb + ty * 4 + i;
        if (row < M)
            #pragma unroll
            for (int j = 0; j < 4; ++j)
                Xout[(size_t)row * 64 + tx * 4 + j] = fmaxf(acc[i][j], 0.f);
    }
}

// ======================= generic GEMM + bias + relu (opt. row gather) =======================
template<bool GATHER>
__global__ __launch_bounds__(256) void gemm_bias_relu(
    const float* __restrict__ A, int lda, const int* __restrict__ idx,
    const float* __restrict__ Bm, const float* __restrict__ bias,
    float* __restrict__ C, int M, int N, int K)
{
    __shared__ float As[64][17];
    __shared__ float Bs[16][64];
    const int rb = blockIdx.x * 64, nb = blockIdx.y * 64;
    const int tid = threadIdx.x, tx = tid & 15, ty = tid >> 4;
    float acc[4][4] = {};
    for (int kb = 0; kb < K; kb += 16) {
        #pragma unroll
        for (int q = 0; q < 4; ++q) {
            int r = (tid >> 4) + q * 16, kc = tid & 15;
            int row = rb + r;
            float v = 0.f;
            if (row < M) {
                size_t ar = GATHER ? (size_t)idx[row] : (size_t)row;
                v = A[ar * lda + kb + kc];
            }
            As[r][kc] = v;
        }
        #pragma unroll
        for (int q = 0; q < 4; ++q) {
            int kr = (tid >> 6) + q * 4, cc = tid & 63;
            Bs[kr][cc] = Bm[(size_t)(kb + kr) * N + nb + cc];
        }
        __syncthreads();
        #pragma unroll
        for (int kk = 0; kk < 16; ++kk) {
            float a0 = As[ty * 4 + 0][kk], a1 = As[ty * 4 + 1][kk];
            float a2 = As[ty * 4 + 2][kk], a3 = As[ty * 4 + 3][kk];
            float4 b4 = *(const float4*)&Bs[kk][tx * 4];
            acc[0][0] += a0 * b4.x; acc[0][1] += a0 * b4.y; acc[0][2] += a0 * b4.z; acc[0][3] += a0 * b4.w;
            acc[1][0] += a1 * b4.x; acc[1][1] += a1 * b4.y; acc[1][2] += a1 * b4.z; acc[1][3] += a1 * b4.w;
            acc[2][0] += a2 * b4.x; acc[2][1] += a2 * b4.y; acc[2][2] += a2 * b4.z; acc[2][3] += a2 * b4.w;
            acc[3][0] += a3 * b4.x; acc[3][1] += a3 * b4.y; acc[3][2] += a3 * b4.z; acc[3][3] += a3 * b4.w;
        }
        __syncthreads();
    }
    #pragma unroll
    for (int i = 0; i < 4; ++i) {
        int row = rb + ty * 4 + i;
        if (row < M)
            #pragma unroll
            for (int j = 0; j < 4; ++j) {
                int col = nb + tx * 4 + j;
                C[(size_t)row * N + col] = fmaxf(acc[i][j] + bias[col], 0.f);
            }
    }
}

// ======================= concat + final head =======================
__global__ void concat_kernel(
    const int* __restrict__ idx_c, const int* __restrict__ idx_p,
    const float* __restrict__ comp_int, const float* __restrict__ Xc,
    const float* __restrict__ fd3, const float* __restrict__ prot_int,
    const float* __restrict__ Xp, const float* __restrict__ fp3,
    float* __restrict__ cat)
{
    int j = blockIdx.x * 256 + threadIdx.x;
    if (j >= BSZ * 384) return;
    int r = j / 384, c = j % 384;
    float v;
    if (c < 64)       v = comp_int[(size_t)idx_c[r] * 64 + c];
    else if (c < 128) v = Xc[(size_t)idx_c[r] * 64 + (c - 64)];
    else if (c < 192) v = fd3[(size_t)r * 64 + (c - 128)];
    else if (c < 256) v = prot_int[(size_t)idx_p[r] * 64 + (c - 192)];
    else if (c < 320) v = Xp[(size_t)idx_p[r] * 64 + (c - 256)];
    else              v = fp3[(size_t)r * 64 + (c - 320)];
    cat[j] = v;
}

__global__ void head_final(
    const float* __restrict__ h3, const float* __restrict__ W_int,
    const float* __restrict__ b_int, float* __restrict__ out)
{
    int r = blockIdx.x * 256 + threadIdx.x;
    if (r >= BSZ) return;
    float s0 = b_int[0], s1 = b_int[1];
    for (int k = 0; k < 256; ++k) {
        float h = h3[(size_t)r * 256 + k];
        s0 += h * W_int[k * 2 + 0];
        s1 += h * W_int[k * 2 + 1];
    }
    out[r * 2 + 0] = 1.f / (1.f + expf(-s0));
    out[r * 2 + 1] = 1.f / (1.f + expf(-s1));
}

// ======================= launch =======================
extern "C" void kernel_launch(void* const* d_in, const int* in_sizes, int n_in,
                              void* d_out, int out_size, void* d_ws, size_t ws_size,
                              hipStream_t stream)
{
    const int*   idx_c        = (const int*)  d_in[0];
    const int*   idx_p        = (const int*)  d_in[1];
    const int*   compounds    = (const int*)  d_in[2];
    const int*   proteins     = (const int*)  d_in[3];
    const float* adjacencies  = (const float*)d_in[4];
    const float* A_c          = (const float*)d_in[5];
    const float* A_p          = (const float*)d_in[6];
    const float* embed_fp     = (const float*)d_in[7];
    const float* embed_word   = (const float*)d_in[8];
    const float* Xs_c         = (const float*)d_in[9];
    const float* Xs_p         = (const float*)d_in[10];
    const float* drug_feat    = (const float*)d_in[11];
    const float* protein_feat = (const float*)d_in[12];
    const float* W_gnn        = (const float*)d_in[13];
    const float* b_gnn        = (const float*)d_in[14];
    const float* K_cnn        = (const float*)d_in[15];
    const float* b_cnn        = (const float*)d_in[16];
    const float* W_gcn_d      = (const float*)d_in[17];
    const float* b_gcn_d      = (const float*)d_in[18];
    const float* W_gcn_p      = (const float*)d_in[19];
    const float* b_gcn_p      = (const float*)d_in[20];
    const float* Wd1 = (const float*)d_in[21]; const float* bd1 = (const float*)d_in[22];
    const float* Wd2 = (const float*)d_in[23]; const float* bd2 = (const float*)d_in[24];
    const float* Wd3 = (const float*)d_in[25]; const float* bd3 = (const float*)d_in[26];
    const float* Wp1 = (const float*)d_in[27]; const float* bp1 = (const float*)d_in[28];
    const float* Wp2 = (const float*)d_in[29]; const float* bp2 = (const float*)d_in[30];
    const float* Wp3 = (const float*)d_in[31]; const float* bp3 = (const float*)d_in[32];
    const float* Wo1 = (const float*)d_in[33]; const float* bo1 = (const float*)d_in[34];
    const float* Wo2 = (const float*)d_in[35]; const float* bo2 = (const float*)d_in[36];
    const float* Wo3 = (const float*)d_in[37]; const float* bo3 = (const float*)d_in[38];
    const float* W_int = (const float*)d_in[39]; const float* b_int = (const float*)d_in[40];

    float* ws = (float*)d_ws;
    float* comp_int  = ws; ws += NC * 64;
    float* prot_part = ws; ws += NP * 16 * 64;
    float* prot_int  = ws; ws += NP * 64;
    float* gcn_part  = ws; ws += 8 * NC * 64;
    float* Xc_a = ws; ws += NC * 64;
    float* Xc_b = ws; ws += NC * 64;
    float* Xp_a = ws; ws += NP * 64;
    float* Xp_b = ws; ws += NP * 64;
    float* fd1 = ws; ws += BSZ * 128;
    float* fd2 = ws; ws += BSZ * 64;
    float* fd3 = ws; ws += BSZ * 64;
    float* fp1 = ws; ws += BSZ * 128;
    float* fp2 = ws; ws += BSZ * 64;
    float* fp3 = ws; ws += BSZ * 64;
    float* cat = ws; ws += BSZ * 384;
    float* h1  = ws; ws += BSZ * 256;
    float* h2m = ws; ws += BSZ * 256;
    float* h3  = ws; ws += BSZ * 256;
    (void)ws_size; (void)in_sizes; (void)n_in; (void)out_size;

    // branch 1: compound GNN
    gnn_kernel<<<NC, 320, 0, stream>>>(compounds, adjacencies, embed_fp, W_gnn, b_gnn, comp_int);
    // branch 2: protein CNN (fp16 dot2, 32-row tiles)
    cnn_kernel<<<dim3(16, NP), 256, 0, stream>>>(proteins, embed_word, K_cnn, b_cnn, prot_part);
    cnn_reduce<<<NP, 64, 0, stream>>>(prot_part, prot_int);
    // branch 3: GCN drug
    spk_gemm64<<<dim3(32, 8), 256, 0, stream>>>(A_c, Xs_c, gcn_part, NC, 256);
    gcn_epi<<<32, 256, 0, stream>>>(gcn_part, 8, NC, W_gcn_d, b_gcn_d, Xc_a);
    spk_gemm64<<<dim3(32, 8), 256, 0, stream>>>(A_c, Xc_a, gcn_part, NC, 256);
    gcn_epi<<<32, 256, 0, stream>>>(gcn_part, 8, NC, W_gcn_d + 4096, b_gcn_d + 64, Xc_b);
    // branch 3b: GCN protein
    spk_gemm64<<<dim3(24, 8), 256, 0, stream>>>(A_p, Xs_p, gcn_part, NP, 192);
    gcn_epi<<<24, 256, 0, stream>>>(gcn_part, 8, NP, W_gcn_p, b_gcn_p, Xp_a);
    spk_gemm64<<<dim3(24, 8), 256, 0, stream>>>(A_p, Xp_a, gcn_part, NP, 192);
    gcn_epi<<<24, 256, 0, stream>>>(gcn_part, 8, NP, W_gcn_p + 4096, b_gcn_p + 64, Xp_b);
    // branch 4: drug MLP
    gemm_bias_relu<true ><<<dim3(64, 2), 256, 0, stream>>>(drug_feat, 1024, idx_c, Wd1, bd1, fd1, BSZ, 128, 1024);
    gemm_bias_relu<false><<<dim3(64, 1), 256, 0, stream>>>(fd1, 128, nullptr, Wd2, bd2, fd2, BSZ, 64, 128);
    gemm_bias_relu<false><<<dim3(64, 1), 256, 0, stream>>>(fd2, 64, nullptr, Wd3, bd3, fd3, BSZ, 64, 64);
    // branch 5: protein MLP
    gemm_bias_relu<true ><<<dim3(64, 2), 256, 0, stream>>>(protein_feat, 1024, idx_p, Wp1, bp1, fp1, BSZ, 128, 1024);
    gemm_bias_relu<false><<<dim3(64, 1), 256, 0, stream>>>(fp1, 128, nullptr, Wp2, bp2, fp2, BSZ, 64, 128);
    gemm_bias_relu<false><<<dim3(64, 1), 256, 0, stream>>>(fp2, 64, nullptr, Wp3, bp3, fp3, BSZ, 64, 64);
    // head
    concat_kernel<<<(BSZ * 384 + 255) / 256, 256, 0, stream>>>(idx_c, idx_p, comp_int, Xc_b, fd3, prot_int, Xp_b, fp3, cat);
    gemm_bias_relu<false><<<dim3(64, 4), 256, 0, stream>>>(cat, 384, nullptr, Wo1, bo1, h1, BSZ, 256, 384);
    gemm_bias_relu<false><<<dim3(64, 4), 256, 0, stream>>>(h1, 256, nullptr, Wo2, bo2, h2m, BSZ, 256, 256);
    gemm_bias_relu<false><<<dim3(64, 4), 256, 0, stream>>>(h2m, 256, nullptr, Wo3, bo3, h3, BSZ, 256, 256);
    head_final<<<(BSZ + 255) / 256, 256, 0, stream>>>(h3, W_int, b_int, (float*)d_out);
}

// Round 7
// 1261.827 us; speedup vs baseline: 4.2512x; 1.2701x over previous
//
#include <hip/hip_runtime.h>
#include <math.h>

#define NC 2000
#define NP 1500
#define NA 40
#define LP 512
#define BSZ 4096

typedef _Float16 half8_t __attribute__((ext_vector_type(8)));
typedef float f32x4 __attribute__((ext_vector_type(4)));

// ======================= GNN (fused per compound) =======================
__global__ __launch_bounds__(320) void gnn_kernel(
    const int* __restrict__ compounds, const float* __restrict__ adjacencies,
    const float* __restrict__ embed_fp, const float* __restrict__ W_gnn,
    const float* __restrict__ b_gnn, float* __restrict__ comp_int)
{
    __shared__ float xs[40][68];
    __shared__ float hs[40][68];
    __shared__ float Ws[64][64];
    __shared__ float adjS[40][41];
    __shared__ float bS[64];
    const int n = blockIdx.x;
    const int tid = threadIdx.x;
    const int a = tid >> 3, g = tid & 7, cb = g * 8;

    for (int j = tid; j < 40 * 64; j += 320) {
        int r = j >> 6, c = j & 63;
        xs[r][c] = embed_fp[(size_t)compounds[n * NA + r] * 64 + c];
    }
    for (int j = tid; j < NA * NA; j += 320)
        adjS[j / NA][j % NA] = adjacencies[(size_t)n * (NA * NA) + j];

    for (int l = 0; l < 3; ++l) {
        __syncthreads();
        for (int j = tid; j < 4096; j += 320) Ws[j >> 6][j & 63] = W_gnn[l * 4096 + j];
        if (tid < 64) bS[tid] = b_gnn[l * 64 + tid];
        __syncthreads();
        float acc[8];
        #pragma unroll
        for (int j = 0; j < 8; ++j) acc[j] = bS[cb + j];
        #pragma unroll 8
        for (int d = 0; d < 64; ++d) {
            float x = xs[a][d];
            float4 w0 = *(const float4*)&Ws[d][cb];
            float4 w1 = *(const float4*)&Ws[d][cb + 4];
            acc[0] += x * w0.x; acc[1] += x * w0.y; acc[2] += x * w0.z; acc[3] += x * w0.w;
            acc[4] += x * w1.x; acc[5] += x * w1.y; acc[6] += x * w1.z; acc[7] += x * w1.w;
        }
        #pragma unroll
        for (int j = 0; j < 8; ++j) hs[a][cb + j] = fmaxf(acc[j], 0.f);
        __syncthreads();
        float4 x0 = *(float4*)&xs[a][cb];
        float4 x1 = *(float4*)&xs[a][cb + 4];
        #pragma unroll 8
        for (int b = 0; b < NA; ++b) {
            float ad = adjS[a][b];
            float4 h0 = *(const float4*)&hs[b][cb];
            float4 h1 = *(const float4*)&hs[b][cb + 4];
            x0.x += ad * h0.x; x0.y += ad * h0.y; x0.z += ad * h0.z; x0.w += ad * h0.w;
            x1.x += ad * h1.x; x1.y += ad * h1.y; x1.z += ad * h1.z; x1.w += ad * h1.w;
        }
        *(float4*)&xs[a][cb] = x0;
        *(float4*)&xs[a][cb + 4] = x1;
    }
    __syncthreads();
    if (tid < 64) {
        float s = 0.f;
        for (int r = 0; r < NA; ++r) s += xs[r][tid];
        comp_int[n * 64 + tid] = s * (1.0f / 40.0f);
    }
}

// ======================= CNN via MFMA (banded 16x16x32 f16) =======================
// Per kernel-row dr:  D[16 rows][16 cols] += A[16][32] * B[32][16]
//   A[m][k] = img[r0-5+dr+m][c0-5+k]   (32 contiguous cols; swizzled ds_read_b128)
//   B[k][n] = K[dr][k-n] for 0<=k-n<11 else 0  (band weights, LDS table -> regs)
// Image LDS row-major, 128 halves/row (256B), 16B-block XOR swizzle: blk ^= row&7.
// 32-row output tiles; rel origin o = t0-15; buffer rows 0..61.
//   stage input rel [0,62); L1 out [5,57) tiles r0={5,21,37,41}; L2 out [10,52)
//   r0={10,26,36}; L3 out [15,47) r0={15,31}. Reads: L1 rows [0,61], L2 [5,56],
//   L3 [10,51] - all within written/zeroed regions. Overlapping tiles rewrite
//   identical values within the same wave (each wave owns one 16-col strip).

__device__ __forceinline__ int swz_off(int row, int half_col)
{
    int b = half_col >> 3;
    return row * 128 + (((b & 8) | ((b ^ row) & 7)) << 3) + (half_col & 7);
}

__global__ __launch_bounds__(256) void cnn_kernel(
    const int* __restrict__ proteins, const float* __restrict__ embed_word,
    const float* __restrict__ K_cnn, const float* __restrict__ b_cnn,
    float* __restrict__ prot_part)
{
    __shared__ half8_t bufA8[62 * 16];
    __shared__ half8_t bufB8[62 * 16];
    __shared__ half8_t wtab[11 * 64];
    _Float16* bufA = (_Float16*)bufA8;
    _Float16* bufB = (_Float16*)bufB8;
    _Float16* wth  = (_Float16*)wtab;

    const int tile = blockIdx.x, p = blockIdx.y;
    const int t0 = tile * 32, tid = threadIdx.x;
    const int lane = tid & 63, wid = tid >> 6;
    const int c0 = wid * 16;            // this wave's column strip
    const int m = lane & 15, g = lane >> 4;

    // zero both buffers (margins must be 0; garbage must never be NaN)
    half8_t z = {};
    for (int q = tid; q < 62 * 16; q += 256) { bufA8[q] = z; bufB8[q] = z; }
    __syncthreads();

    // stage input rows rel [0,62) = global [t0-15, t0+47), cols 0..63 -> padded col+13
    for (int e = tid; e < 62 * 64; e += 256) {
        int i = e >> 6, cc = e & 63, gr = t0 - 15 + i;
        if (gr >= 0 && gr < LP) {
            float v = embed_word[(size_t)proteins[p * LP + gr] * 64 + cc];
            bufA[swz_off(i, cc + 13)] = (_Float16)v;
        }
    }

    half8_t wf[11];

    auto fill_wtab = [&](int L) {
        for (int h = tid; h < 5632; h += 256) {
            int dr = h >> 9, rem = h & 511, ln = rem >> 3, i = rem & 7;
            int dc = 8 * (ln >> 4) + i - (ln & 15);
            float v = (dc >= 0 && dc < 11) ? K_cnn[L * 121 + dr * 11 + dc] : 0.f;
            wth[h] = (_Float16)v;
        }
    };
    auto load_wf = [&]() {
        #pragma unroll
        for (int dr = 0; dr < 11; ++dr) wf[dr] = wtab[dr * 64 + lane];
    };
    auto conv_tile = [&](const _Float16* src, int r0, float bias) -> f32x4 {
        f32x4 acc = {bias, bias, bias, bias};
        const int B0 = (c0 + 8) >> 3;
        #pragma unroll
        for (int dr = 0; dr < 11; ++dr) {
            int R = r0 - 5 + dr + m;
            int b = B0 + g;
            half8_t a = *(const half8_t*)&src[R * 128 + (((b & 8) | ((b ^ R) & 7)) << 3)];
            acc = __builtin_amdgcn_mfma_f32_16x16x32_f16(a, wf[dr], acc, 0, 0, 0);
        }
        return acc;
    };
    auto store_tile = [&](_Float16* dst, int r0, f32x4 acc) {
        int pc = c0 + 13 + m;
        #pragma unroll
        for (int j = 0; j < 4; ++j) {
            int row = r0 + 4 * g + j;
            int og = t0 - 15 + row;
            float v = fmaxf(acc[j], 0.f);
            dst[swz_off(row, pc)] = (_Float16)((og >= 0 && og < LP) ? v : 0.f);
        }
    };

    __syncthreads();
    // ---- layer 1: bufA -> bufB
    fill_wtab(0); __syncthreads(); load_wf();
    {
        float b0 = b_cnn[0];
        const int r0s[4] = {5, 21, 37, 41};
        #pragma unroll
        for (int k = 0; k < 4; ++k) store_tile(bufB, r0s[k], conv_tile(bufA, r0s[k], b0));
    }
    __syncthreads();
    // ---- layer 2: bufB -> bufA
    fill_wtab(1); __syncthreads(); load_wf();
    {
        float b1 = b_cnn[1];
        const int r0s[3] = {10, 26, 36};
        #pragma unroll
        for (int k = 0; k < 3; ++k) store_tile(bufA, r0s[k], conv_tile(bufB, r0s[k], b1));
    }
    __syncthreads();
    // ---- layer 3: bufA -> column sums over rows rel [15,47)
    fill_wtab(2); __syncthreads(); load_wf();
    {
        float b2 = b_cnn[2];
        float cs = 0.f;
        const int r0s[2] = {15, 31};
        #pragma unroll
        for (int k = 0; k < 2; ++k) {
            f32x4 acc = conv_tile(bufA, r0s[k], b2);
            #pragma unroll
            for (int j = 0; j < 4; ++j) cs += fmaxf(acc[j], 0.f);
        }
        cs += __shfl_xor(cs, 16, 64);
        cs += __shfl_xor(cs, 32, 64);
        if (lane < 16)
            prot_part[((size_t)p * 16 + tile) * 64 + c0 + lane] = cs;
    }
}

__global__ void cnn_reduce(const float* __restrict__ prot_part, float* __restrict__ prot_int)
{
    const int p = blockIdx.x, c = threadIdx.x;
    float s = 0.f;
    for (int t = 0; t < 16; ++t) s += prot_part[((size_t)p * 16 + t) * 64 + c];
    prot_int[p * 64 + c] = s * (1.0f / 512.0f);
}

// ======================= GCN: split-K GEMM (N=64) + epilogue =======================
__global__ __launch_bounds__(256) void spk_gemm64(
    const float* __restrict__ A, const float* __restrict__ X,
    float* __restrict__ part, int M, int kchunk)
{
    __shared__ float As[64][17];
    __shared__ float Xs[16][64];
    const int rb = blockIdx.x * 64;
    const int s = blockIdx.y;
    const int k0 = s * kchunk;
    const int k1 = (k0 + kchunk < M) ? (k0 + kchunk) : M;
    const int tid = threadIdx.x, tx = tid & 15, ty = tid >> 4;
    float acc[4][4] = {};
    for (int kb = k0; kb < k1; kb += 16) {
        #pragma unroll
        for (int q = 0; q < 4; ++q) {
            int r = (tid >> 4) + q * 16, kc = tid & 15;
            int row = rb + r, kidx = kb + kc;
            As[r][kc] = (row < M && kidx < k1) ? A[(size_t)row * M + kidx] : 0.f;
        }
        #pragma unroll
        for (int q = 0; q < 4; ++q) {
            int kr = (tid >> 6) + q * 4, cc = tid & 63;
            int kidx = kb + kr;
            Xs[kr][cc] = (kidx < k1) ? X[(size_t)kidx * 64 + cc] : 0.f;
        }
        __syncthreads();
        #pragma unroll
        for (int kk = 0; kk < 16; ++kk) {
            float a0 = As[ty * 4 + 0][kk], a1 = As[ty * 4 + 1][kk];
            float a2 = As[ty * 4 + 2][kk], a3 = As[ty * 4 + 3][kk];
            float4 b4 = *(const float4*)&Xs[kk][tx * 4];
            acc[0][0] += a0 * b4.x; acc[0][1] += a0 * b4.y; acc[0][2] += a0 * b4.z; acc[0][3] += a0 * b4.w;
            acc[1][0] += a1 * b4.x; acc[1][1] += a1 * b4.y; acc[1][2] += a1 * b4.z; acc[1][3] += a1 * b4.w;
            acc[2][0] += a2 * b4.x; acc[2][1] += a2 * b4.y; acc[2][2] += a2 * b4.z; acc[2][3] += a2 * b4.w;
            acc[3][0] += a3 * b4.x; acc[3][1] += a3 * b4.y; acc[3][2] += a3 * b4.z; acc[3][3] += a3 * b4.w;
        }
        __syncthreads();
    }
    #pragma unroll
    for (int i = 0; i < 4; ++i) {
        int row = rb + ty * 4 + i;
        if (row < M)
            *(float4*)&part[((size_t)s * M + row) * 64 + tx * 4] =
                make_float4(acc[i][0], acc[i][1], acc[i][2], acc[i][3]);
    }
}

__global__ __launch_bounds__(256) void gcn_epi(
    const float* __restrict__ part, int S, int M,
    const float* __restrict__ W, const float* __restrict__ bias,
    float* __restrict__ Xout)
{
    __shared__ float Ys[64][68];
    __shared__ float Ws[64][64];
    const int rb = blockIdx.x * 64;
    const int tid = threadIdx.x;
    for (int j = tid; j < 4096; j += 256) Ws[j >> 6][j & 63] = W[j];
    for (int j = tid; j < 4096; j += 256) {
        int r = j >> 6, c = j & 63;
        float sum = 0.f;
        if (rb + r < M)
            for (int t = 0; t < S; ++t) sum += part[((size_t)t * M + rb + r) * 64 + c];
        Ys[r][c] = sum;
    }
    __syncthreads();
    const int tx = tid & 15, ty = tid >> 4;
    float acc[4][4];
    #pragma unroll
    for (int i = 0; i < 4; ++i)
        #pragma unroll
        for (int j = 0; j < 4; ++j) acc[i][j] = bias[tx * 4 + j];
    for (int d = 0; d < 64; ++d) {
        float a0 = Ys[ty * 4 + 0][d], a1 = Ys[ty * 4 + 1][d];
        float a2 = Ys[ty * 4 + 2][d], a3 = Ys[ty * 4 + 3][d];
        float4 w4 = *(const float4*)&Ws[d][tx * 4];
        acc[0][0] += a0 * w4.x; acc[0][1] += a0 * w4.y; acc[0][2] += a0 * w4.z; acc[0][3] += a0 * w4.w;
        acc[1][0] += a1 * w4.x; acc[1][1] += a1 * w4.y; acc[1][2] += a1 * w4.z; acc[1][3] += a1 * w4.w;
        acc[2][0] += a2 * w4.x; acc[2][1] += a2 * w4.y; acc[2][2] += a2 * w4.z; acc[2][3] += a2 * w4.w;
        acc[3][0] += a3 * w4.x; acc[3][1] += a3 * w4.y; acc[3][2] += a3 * w4.z; acc[3][3] += a3 * w4.w;
    }
    #pragma unroll
    for (int i = 0; i < 4; ++i) {
        int row = rb + ty * 4 + i;
        if (row < M)
            #pragma unroll
            for (int j = 0; j < 4; ++j)
                Xout[(size_t)row * 64 + tx * 4 + j] = fmaxf(acc[i][j], 0.f);
    }
}

// ======================= generic GEMM + bias + relu (opt. row gather) =======================
template<bool GATHER>
__global__ __launch_bounds__(256) void gemm_bias_relu(
    const float* __restrict__ A, int lda, const int* __restrict__ idx,
    const float* __restrict__ Bm, const float* __restrict__ bias,
    float* __restrict__ C, int M, int N, int K)
{
    __shared__ float As[64][17];
    __shared__ float Bs[16][64];
    const int rb = blockIdx.x * 64, nb = blockIdx.y * 64;
    const int tid = threadIdx.x, tx = tid & 15, ty = tid >> 4;
    float acc[4][4] = {};
    for (int kb = 0; kb < K; kb += 16) {
        #pragma unroll
        for (int q = 0; q < 4; ++q) {
            int r = (tid >> 4) + q * 16, kc = tid & 15;
            int row = rb + r;
            float v = 0.f;
            if (row < M) {
                size_t ar = GATHER ? (size_t)idx[row] : (size_t)row;
                v = A[ar * lda + kb + kc];
            }
            As[r][kc] = v;
        }
        #pragma unroll
        for (int q = 0; q < 4; ++q) {
            int kr = (tid >> 6) + q * 4, cc = tid & 63;
            Bs[kr][cc] = Bm[(size_t)(kb + kr) * N + nb + cc];
        }
        __syncthreads();
        #pragma unroll
        for (int kk = 0; kk < 16; ++kk) {
            float a0 = As[ty * 4 + 0][kk], a1 = As[ty * 4 + 1][kk];
            float a2 = As[ty * 4 + 2][kk], a3 = As[ty * 4 + 3][kk];
            float4 b4 = *(const float4*)&Bs[kk][tx * 4];
            acc[0][0] += a0 * b4.x; acc[0][1] += a0 * b4.y; acc[0][2] += a0 * b4.z; acc[0][3] += a0 * b4.w;
            acc[1][0] += a1 * b4.x; acc[1][1] += a1 * b4.y; acc[1][2] += a1 * b4.z; acc[1][3] += a1 * b4.w;
            acc[2][0] += a2 * b4.x; acc[2][1] += a2 * b4.y; acc[2][2] += a2 * b4.z; acc[2][3] += a2 * b4.w;
            acc[3][0] += a3 * b4.x; acc[3][1] += a3 * b4.y; acc[3][2] += a3 * b4.z; acc[3][3] += a3 * b4.w;
        }
        __syncthreads();
    }
    #pragma unroll
    for (int i = 0; i < 4; ++i) {
        int row = rb + ty * 4 + i;
        if (row < M)
            #pragma unroll
            for (int j = 0; j < 4; ++j) {
                int col = nb + tx * 4 + j;
                C[(size_t)row * N + col] = fmaxf(acc[i][j] + bias[col], 0.f);
            }
    }
}

// ======================= concat + final head =======================
__global__ void concat_kernel(
    const int* __restrict__ idx_c, const int* __restrict__ idx_p,
    const float* __restrict__ comp_int, const float* __restrict__ Xc,
    const float* __restrict__ fd3, const float* __restrict__ prot_int,
    const float* __restrict__ Xp, const float* __restrict__ fp3,
    float* __restrict__ cat)
{
    int j = blockIdx.x * 256 + threadIdx.x;
    if (j >= BSZ * 384) return;
    int r = j / 384, c = j % 384;
    float v;
    if (c < 64)       v = comp_int[(size_t)idx_c[r] * 64 + c];
    else if (c < 128) v = Xc[(size_t)idx_c[r] * 64 + (c - 64)];
    else if (c < 192) v = fd3[(size_t)r * 64 + (c - 128)];
    else if (c < 256) v = prot_int[(size_t)idx_p[r] * 64 + (c - 192)];
    else if (c < 320) v = Xp[(size_t)idx_p[r] * 64 + (c - 256)];
    else              v = fp3[(size_t)r * 64 + (c - 320)];
    cat[j] = v;
}

__global__ void head_final(
    const float* __restrict__ h3, const float* __restrict__ W_int,
    const float* __restrict__ b_int, float* __restrict__ out)
{
    int r = blockIdx.x * 256 + threadIdx.x;
    if (r >= BSZ) return;
    float s0 = b_int[0], s1 = b_int[1];
    for (int k = 0; k < 256; ++k) {
        float h = h3[(size_t)r * 256 + k];
        s0 += h * W_int[k * 2 + 0];
        s1 += h * W_int[k * 2 + 1];
    }
    out[r * 2 + 0] = 1.f / (1.f + expf(-s0));
    out[r * 2 + 1] = 1.f / (1.f + expf(-s1));
}

// ======================= launch =======================
extern "C" void kernel_launch(void* const* d_in, const int* in_sizes, int n_in,
                              void* d_out, int out_size, void* d_ws, size_t ws_size,
                              hipStream_t stream)
{
    const int*   idx_c        = (const int*)  d_in[0];
    const int*   idx_p        = (const int*)  d_in[1];
    const int*   compounds    = (const int*)  d_in[2];
    const int*   proteins     = (const int*)  d_in[3];
    const float* adjacencies  = (const float*)d_in[4];
    const float* A_c          = (const float*)d_in[5];
    const float* A_p          = (const float*)d_in[6];
    const float* embed_fp     = (const float*)d_in[7];
    const float* embed_word   = (const float*)d_in[8];
    const float* Xs_c         = (const float*)d_in[9];
    const float* Xs_p         = (const float*)d_in[10];
    const float* drug_feat    = (const float*)d_in[11];
    const float* protein_feat = (const float*)d_in[12];
    const float* W_gnn        = (const float*)d_in[13];
    const float* b_gnn        = (const float*)d_in[14];
    const float* K_cnn        = (const float*)d_in[15];
    const float* b_cnn        = (const float*)d_in[16];
    const float* W_gcn_d      = (const float*)d_in[17];
    const float* b_gcn_d      = (const float*)d_in[18];
    const float* W_gcn_p      = (const float*)d_in[19];
    const float* b_gcn_p      = (const float*)d_in[20];
    const float* Wd1 = (const float*)d_in[21]; const float* bd1 = (const float*)d_in[22];
    const float* Wd2 = (const float*)d_in[23]; const float* bd2 = (const float*)d_in[24];
    const float* Wd3 = (const float*)d_in[25]; const float* bd3 = (const float*)d_in[26];
    const float* Wp1 = (const float*)d_in[27]; const float* bp1 = (const float*)d_in[28];
    const float* Wp2 = (const float*)d_in[29]; const float* bp2 = (const float*)d_in[30];
    const float* Wp3 = (const float*)d_in[31]; const float* bp3 = (const float*)d_in[32];
    const float* Wo1 = (const float*)d_in[33]; const float* bo1 = (const float*)d_in[34];
    const float* Wo2 = (const float*)d_in[35]; const float* bo2 = (const float*)d_in[36];
    const float* Wo3 = (const float*)d_in[37]; const float* bo3 = (const float*)d_in[38];
    const float* W_int = (const float*)d_in[39]; const float* b_int = (const float*)d_in[40];

    float* ws = (float*)d_ws;
    float* comp_int  = ws; ws += NC * 64;
    float* prot_part = ws; ws += NP * 16 * 64;
    float* prot_int  = ws; ws += NP * 64;
    float* gcn_part  = ws; ws += 8 * NC * 64;
    float* Xc_a = ws; ws += NC * 64;
    float* Xc_b = ws; ws += NC * 64;
    float* Xp_a = ws; ws += NP * 64;
    float* Xp_b = ws; ws += NP * 64;
    float* fd1 = ws; ws += BSZ * 128;
    float* fd2 = ws; ws += BSZ * 64;
    float* fd3 = ws; ws += BSZ * 64;
    float* fp1 = ws; ws += BSZ * 128;
    float* fp2 = ws; ws += BSZ * 64;
    float* fp3 = ws; ws += BSZ * 64;
    float* cat = ws; ws += BSZ * 384;
    float* h1  = ws; ws += BSZ * 256;
    float* h2m = ws; ws += BSZ * 256;
    float* h3  = ws; ws += BSZ * 256;
    (void)ws_size; (void)in_sizes; (void)n_in; (void)out_size;

    // branch 1: compound GNN
    gnn_kernel<<<NC, 320, 0, stream>>>(compounds, adjacencies, embed_fp, W_gnn, b_gnn, comp_int);
    // branch 2: protein CNN (banded MFMA, 32-row tiles)
    cnn_kernel<<<dim3(16, NP), 256, 0, stream>>>(proteins, embed_word, K_cnn, b_cnn, prot_part);
    cnn_reduce<<<NP, 64, 0, stream>>>(prot_part, prot_int);
    // branch 3: GCN drug
    spk_gemm64<<<dim3(32, 8), 256, 0, stream>>>(A_c, Xs_c, gcn_part, NC, 256);
    gcn_epi<<<32, 256, 0, stream>>>(gcn_part, 8, NC, W_gcn_d, b_gcn_d, Xc_a);
    spk_gemm64<<<dim3(32, 8), 256, 0, stream>>>(A_c, Xc_a, gcn_part, NC, 256);
    gcn_epi<<<32, 256, 0, stream>>>(gcn_part, 8, NC, W_gcn_d + 4096, b_gcn_d + 64, Xc_b);
    // branch 3b: GCN protein
    spk_gemm64<<<dim3(24, 8), 256, 0, stream>>>(A_p, Xs_p, gcn_part, NP, 192);
    gcn_epi<<<24, 256, 0, stream>>>(gcn_part, 8, NP, W_gcn_p, b_gcn_p, Xp_a);
    spk_gemm64<<<dim3(24, 8), 256, 0, stream>>>(A_p, Xp_a, gcn_part, NP, 192);
    gcn_epi<<<24, 256, 0, stream>>>(gcn_part, 8, NP, W_gcn_p + 4096, b_gcn_p + 64, Xp_b);
    // branch 4: drug MLP
    gemm_bias_relu<true ><<<dim3(64, 2), 256, 0, stream>>>(drug_feat, 1024, idx_c, Wd1, bd1, fd1, BSZ, 128, 1024);
    gemm_bias_relu<false><<<dim3(64, 1), 256, 0, stream>>>(fd1, 128, nullptr, Wd2, bd2, fd2, BSZ, 64, 128);
    gemm_bias_relu<false><<<dim3(64, 1), 256, 0, stream>>>(fd2, 64, nullptr, Wd3, bd3, fd3, BSZ, 64, 64);
    // branch 5: protein MLP
    gemm_bias_relu<true ><<<dim3(64, 2), 256, 0, stream>>>(protein_feat, 1024, idx_p, Wp1, bp1, fp1, BSZ, 128, 1024);
    gemm_bias_relu<false><<<dim3(64, 1), 256, 0, stream>>>(fp1, 128, nullptr, Wp2, bp2, fp2, BSZ, 64, 128);
    gemm_bias_relu<false><<<dim3(64, 1), 256, 0, stream>>>(fp2, 64, nullptr, Wp3, bp3, fp3, BSZ, 64, 64);
    // head
    concat_kernel<<<(BSZ * 384 + 255) / 256, 256, 0, stream>>>(idx_c, idx_p, comp_int, Xc_b, fd3, prot_int, Xp_b, fp3, cat);
    gemm_bias_relu<false><<<dim3(64, 4), 256, 0, stream>>>(cat, 384, nullptr, Wo1, bo1, h1, BSZ, 256, 384);
    gemm_bias_relu<false><<<dim3(64, 4), 256, 0, stream>>>(h1, 256, nullptr, Wo2, bo2, h2m, BSZ, 256, 256);
    gemm_bias_relu<false><<<dim3(64, 4), 256, 0, stream>>>(h2m, 256, nullptr, Wo3, bo3, h3, BSZ, 256, 256);
    head_final<<<(BSZ + 255) / 256, 256, 0, stream>>>(h3, W_int, b_int, (float*)d_out);
}

// Round 8
// 1029.961 us; speedup vs baseline: 5.2082x; 1.2251x over previous
//
#include <hip/hip_runtime.h>
#include <math.h>

#define NC 2000
#define NP 1500
#define NA 40
#define LP 512
#define BSZ 4096

typedef _Float16 half8_t __attribute__((ext_vector_type(8)));
typedef float f32x4 __attribute__((ext_vector_type(4)));

// ======================= GNN (fused per compound) =======================
__global__ __launch_bounds__(320) void gnn_kernel(
    const int* __restrict__ compounds, const float* __restrict__ adjacencies,
    const float* __restrict__ embed_fp, const float* __restrict__ W_gnn,
    const float* __restrict__ b_gnn, float* __restrict__ comp_int)
{
    __shared__ float xs[40][68];
    __shared__ float hs[40][68];
    __shared__ float Ws[64][64];
    __shared__ float adjS[40][41];
    __shared__ float bS[64];
    const int n = blockIdx.x;
    const int tid = threadIdx.x;
    const int a = tid >> 3, g = tid & 7, cb = g * 8;

    for (int j = tid; j < 40 * 64; j += 320) {
        int r = j >> 6, c = j & 63;
        xs[r][c] = embed_fp[(size_t)compounds[n * NA + r] * 64 + c];
    }
    for (int j = tid; j < NA * NA; j += 320)
        adjS[j / NA][j % NA] = adjacencies[(size_t)n * (NA * NA) + j];

    for (int l = 0; l < 3; ++l) {
        __syncthreads();
        for (int j = tid; j < 4096; j += 320) Ws[j >> 6][j & 63] = W_gnn[l * 4096 + j];
        if (tid < 64) bS[tid] = b_gnn[l * 64 + tid];
        __syncthreads();
        float acc[8];
        #pragma unroll
        for (int j = 0; j < 8; ++j) acc[j] = bS[cb + j];
        #pragma unroll 8
        for (int d = 0; d < 64; ++d) {
            float x = xs[a][d];
            float4 w0 = *(const float4*)&Ws[d][cb];
            float4 w1 = *(const float4*)&Ws[d][cb + 4];
            acc[0] += x * w0.x; acc[1] += x * w0.y; acc[2] += x * w0.z; acc[3] += x * w0.w;
            acc[4] += x * w1.x; acc[5] += x * w1.y; acc[6] += x * w1.z; acc[7] += x * w1.w;
        }
        #pragma unroll
        for (int j = 0; j < 8; ++j) hs[a][cb + j] = fmaxf(acc[j], 0.f);
        __syncthreads();
        float4 x0 = *(float4*)&xs[a][cb];
        float4 x1 = *(float4*)&xs[a][cb + 4];
        #pragma unroll 8
        for (int b = 0; b < NA; ++b) {
            float ad = adjS[a][b];
            float4 h0 = *(const float4*)&hs[b][cb];
            float4 h1 = *(const float4*)&hs[b][cb + 4];
            x0.x += ad * h0.x; x0.y += ad * h0.y; x0.z += ad * h0.z; x0.w += ad * h0.w;
            x1.x += ad * h1.x; x1.y += ad * h1.y; x1.z += ad * h1.z; x1.w += ad * h1.w;
        }
        *(float4*)&xs[a][cb] = x0;
        *(float4*)&xs[a][cb + 4] = x1;
    }
    __syncthreads();
    if (tid < 64) {
        float s = 0.f;
        for (int r = 0; r < NA; ++r) s += xs[r][tid];
        comp_int[n * 64 + tid] = s * (1.0f / 40.0f);
    }
}

// ======================= CNN via MFMA (banded 16x16x32 f16) =======================
// Per kernel-row dr:  D[16 rows][16 cols] += A[16][32] * B[32][16]
//   A[m][k] = img[r0-5+dr+m][c0-5+k]   (32 contiguous cols; swizzled ds_read_b128)
//   B[k][n] = K[dr][k-n] for 0<=k-n<11 else 0  (band weights, precomputed in
//   global by cnn_wtab; L2-resident, loaded per layer into 11 reg fragments)
// Image LDS row-major, 128 halves/row (256B), 16B-block XOR swizzle: blk ^= row&7.
// 32-row output tiles; rel origin o = t0-15; buffer rows 0..61.
//   stage input rel [0,62); L1 out [5,57) tiles r0={5,21,37,41}; L2 out [10,52)
//   r0={10,26,36}; L3 out [15,47) r0={15,31}. Reads: L1 rows [0,61], L2 [5,56],
//   L3 [10,51] - all within written/zeroed regions. Overlapping tiles rewrite
//   identical values within the same wave (each wave owns one 16-col strip).

__device__ __forceinline__ int swz_off(int row, int half_col)
{
    int b = half_col >> 3;
    return row * 128 + (((b & 8) | ((b ^ row) & 7)) << 3) + (half_col & 7);
}

// build wtab[L][dr][lane] (half8 each): B-fragment for lane = 8 k-halves
__global__ void cnn_wtab(const float* __restrict__ K_cnn, _Float16* __restrict__ wtab)
{
    int h = blockIdx.x * 256 + threadIdx.x;
    if (h < 3 * 11 * 512) {
        int L = h / 5632, rem = h % 5632;
        int dr = rem >> 9, r2 = rem & 511, ln = r2 >> 3, i = r2 & 7;
        int dc = 8 * (ln >> 4) + i - (ln & 15);   // k - n
        float v = (dc >= 0 && dc < 11) ? K_cnn[L * 121 + dr * 11 + dc] : 0.f;
        wtab[h] = (_Float16)v;
    }
}

__global__ __launch_bounds__(256) void cnn_kernel(
    const int* __restrict__ proteins, const float* __restrict__ embed_word,
    const half8_t* __restrict__ wtab, const float* __restrict__ b_cnn,
    float* __restrict__ prot_part)
{
    __shared__ half8_t bufA8[62 * 16];
    __shared__ half8_t bufB8[62 * 16];
    _Float16* bufA = (_Float16*)bufA8;
    _Float16* bufB = (_Float16*)bufB8;

    const int tile = blockIdx.x, p = blockIdx.y;
    const int t0 = tile * 32, tid = threadIdx.x;
    const int lane = tid & 63, wid = tid >> 6;
    const int c0 = wid * 16;            // this wave's column strip
    const int m = lane & 15, g = lane >> 4;

    // zero both buffers (margins must be 0; garbage must never be NaN)
    half8_t z = {};
    for (int q = tid; q < 62 * 16; q += 256) { bufA8[q] = z; bufB8[q] = z; }
    __syncthreads();

    // stage input rows rel [0,62) = global [t0-15, t0+47), cols 0..63 -> padded col+13
    for (int e = tid; e < 62 * 64; e += 256) {
        int i = e >> 6, cc = e & 63, gr = t0 - 15 + i;
        if (gr >= 0 && gr < LP) {
            float v = embed_word[(size_t)proteins[p * LP + gr] * 64 + cc];
            bufA[swz_off(i, cc + 13)] = (_Float16)v;
        }
    }

    half8_t wf[11];
    auto load_wf = [&](int L) {
        #pragma unroll
        for (int dr = 0; dr < 11; ++dr) wf[dr] = wtab[L * 11 * 64 + dr * 64 + lane];
    };
    auto conv_tile = [&](const _Float16* src, int r0, float bias) -> f32x4 {
        f32x4 acc = {bias, bias, bias, bias};
        const int B0 = (c0 + 8) >> 3;
        #pragma unroll
        for (int dr = 0; dr < 11; ++dr) {
            int R = r0 - 5 + dr + m;
            int b = B0 + g;
            half8_t a = *(const half8_t*)&src[R * 128 + (((b & 8) | ((b ^ R) & 7)) << 3)];
            acc = __builtin_amdgcn_mfma_f32_16x16x32_f16(a, wf[dr], acc, 0, 0, 0);
        }
        return acc;
    };
    auto store_tile = [&](_Float16* dst, int r0, f32x4 acc) {
        int pc = c0 + 13 + m;
        #pragma unroll
        for (int j = 0; j < 4; ++j) {
            int row = r0 + 4 * g + j;
            int og = t0 - 15 + row;
            float v = fmaxf(acc[j], 0.f);
            dst[swz_off(row, pc)] = (_Float16)((og >= 0 && og < LP) ? v : 0.f);
        }
    };

    // ---- layer 1: bufA -> bufB
    load_wf(0);
    __syncthreads();
    {
        float b0 = b_cnn[0];
        const int r0s[4] = {5, 21, 37, 41};
        #pragma unroll
        for (int k = 0; k < 4; ++k) store_tile(bufB, r0s[k], conv_tile(bufA, r0s[k], b0));
    }
    __syncthreads();
    // ---- layer 2: bufB -> bufA
    load_wf(1);
    {
        float b1 = b_cnn[1];
        const int r0s[3] = {10, 26, 36};
        #pragma unroll
        for (int k = 0; k < 3; ++k) store_tile(bufA, r0s[k], conv_tile(bufB, r0s[k], b1));
    }
    __syncthreads();
    // ---- layer 3: bufA -> column sums over rows rel [15,47)
    load_wf(2);
    {
        float b2 = b_cnn[2];
        float cs = 0.f;
        const int r0s[2] = {15, 31};
        #pragma unroll
        for (int k = 0; k < 2; ++k) {
            f32x4 acc = conv_tile(bufA, r0s[k], b2);
            #pragma unroll
            for (int j = 0; j < 4; ++j) cs += fmaxf(acc[j], 0.f);
        }
        cs += __shfl_xor(cs, 16, 64);
        cs += __shfl_xor(cs, 32, 64);
        if (lane < 16)
            prot_part[((size_t)p * 16 + tile) * 64 + c0 + lane] = cs;
    }
}

__global__ void cnn_reduce(const float* __restrict__ prot_part, float* __restrict__ prot_int)
{
    const int p = blockIdx.x, c = threadIdx.x;
    float s = 0.f;
    for (int t = 0; t < 16; ++t) s += prot_part[((size_t)p * 16 + t) * 64 + c];
    prot_int[p * 64 + c] = s * (1.0f / 512.0f);
}

// ======================= GCN: split-K GEMM (N=64) + epilogue =======================
__global__ __launch_bounds__(256) void spk_gemm64(
    const float* __restrict__ A, const float* __restrict__ X,
    float* __restrict__ part, int M, int kchunk)
{
    __shared__ float As[64][17];
    __shared__ float Xs[16][64];
    const int rb = blockIdx.x * 64;
    const int s = blockIdx.y;
    const int k0 = s * kchunk;
    const int k1 = (k0 + kchunk < M) ? (k0 + kchunk) : M;
    const int tid = threadIdx.x, tx = tid & 15, ty = tid >> 4;
    float acc[4][4] = {};
    for (int kb = k0; kb < k1; kb += 16) {
        #pragma unroll
        for (int q = 0; q < 4; ++q) {
            int r = (tid >> 4) + q * 16, kc = tid & 15;
            int row = rb + r, kidx = kb + kc;
            As[r][kc] = (row < M && kidx < k1) ? A[(size_t)row * M + kidx] : 0.f;
        }
        #pragma unroll
        for (int q = 0; q < 4; ++q) {
            int kr = (tid >> 6) + q * 4, cc = tid & 63;
            int kidx = kb + kr;
            Xs[kr][cc] = (kidx < k1) ? X[(size_t)kidx * 64 + cc] : 0.f;
        }
        __syncthreads();
        #pragma unroll
        for (int kk = 0; kk < 16; ++kk) {
            float a0 = As[ty * 4 + 0][kk], a1 = As[ty * 4 + 1][kk];
            float a2 = As[ty * 4 + 2][kk], a3 = As[ty * 4 + 3][kk];
            float4 b4 = *(const float4*)&Xs[kk][tx * 4];
            acc[0][0] += a0 * b4.x; acc[0][1] += a0 * b4.y; acc[0][2] += a0 * b4.z; acc[0][3] += a0 * b4.w;
            acc[1][0] += a1 * b4.x; acc[1][1] += a1 * b4.y; acc[1][2] += a1 * b4.z; acc[1][3] += a1 * b4.w;
            acc[2][0] += a2 * b4.x; acc[2][1] += a2 * b4.y; acc[2][2] += a2 * b4.z; acc[2][3] += a2 * b4.w;
            acc[3][0] += a3 * b4.x; acc[3][1] += a3 * b4.y; acc[3][2] += a3 * b4.z; acc[3][3] += a3 * b4.w;
        }
        __syncthreads();
    }
    #pragma unroll
    for (int i = 0; i < 4; ++i) {
        int row = rb + ty * 4 + i;
        if (row < M)
            *(float4*)&part[((size_t)s * M + row) * 64 + tx * 4] =
                make_float4(acc[i][0], acc[i][1], acc[i][2], acc[i][3]);
    }
}

__global__ __launch_bounds__(256) void gcn_epi(
    const float* __restrict__ part, int S, int M,
    const float* __restrict__ W, const float* __restrict__ bias,
    float* __restrict__ Xout)
{
    __shared__ float Ys[64][68];
    __shared__ float Ws[64][64];
    const int rb = blockIdx.x * 64;
    const int tid = threadIdx.x;
    for (int j = tid; j < 4096; j += 256) Ws[j >> 6][j & 63] = W[j];
    for (int j = tid; j < 4096; j += 256) {
        int r = j >> 6, c = j & 63;
        float sum = 0.f;
        if (rb + r < M)
            for (int t = 0; t < S; ++t) sum += part[((size_t)t * M + rb + r) * 64 + c];
        Ys[r][c] = sum;
    }
    __syncthreads();
    const int tx = tid & 15, ty = tid >> 4;
    float acc[4][4];
    #pragma unroll
    for (int i = 0; i < 4; ++i)
        #pragma unroll
        for (int j = 0; j < 4; ++j) acc[i][j] = bias[tx * 4 + j];
    for (int d = 0; d < 64; ++d) {
        float a0 = Ys[ty * 4 + 0][d], a1 = Ys[ty * 4 + 1][d];
        float a2 = Ys[ty * 4 + 2][d], a3 = Ys[ty * 4 + 3][d];
        float4 w4 = *(const float4*)&Ws[d][tx * 4];
        acc[0][0] += a0 * w4.x; acc[0][1] += a0 * w4.y; acc[0][2] += a0 * w4.z; acc[0][3] += a0 * w4.w;
        acc[1][0] += a1 * w4.x; acc[1][1] += a1 * w4.y; acc[1][2] += a1 * w4.z; acc[1][3] += a1 * w4.w;
        acc[2][0] += a2 * w4.x; acc[2][1] += a2 * w4.y; acc[2][2] += a2 * w4.z; acc[2][3] += a2 * w4.w;
        acc[3][0] += a3 * w4.x; acc[3][1] += a3 * w4.y; acc[3][2] += a3 * w4.z; acc[3][3] += a3 * w4.w;
    }
    #pragma unroll
    for (int i = 0; i < 4; ++i) {
        int row = rb + ty * 4 + i;
        if (row < M)
            #pragma unroll
            for (int j = 0; j < 4; ++j)
                Xout[(size_t)row * 64 + tx * 4 + j] = fmaxf(acc[i][j], 0.f);
    }
}

// ======================= generic GEMM + bias + relu (opt. row gather) =======================
template<bool GATHER>
__global__ __launch_bounds__(256) void gemm_bias_relu(
    const float* __restrict__ A, int lda, const int* __restrict__ idx,
    const float* __restrict__ Bm, const float* __restrict__ bias,
    float* __restrict__ C, int M, int N, int K)
{
    __shared__ float As[64][17];
    __shared__ float Bs[16][64];
    const int rb = blockIdx.x * 64, nb = blockIdx.y * 64;
    const int tid = threadIdx.x, tx = tid & 15, ty = tid >> 4;
    float acc[4][4] = {};
    for (int kb = 0; kb < K; kb += 16) {
        #pragma unroll
        for (int q = 0; q < 4; ++q) {
            int r = (tid >> 4) + q * 16, kc = tid & 15;
            int row = rb + r;
            float v = 0.f;
            if (row < M) {
                size_t ar = GATHER ? (size_t)idx[row] : (size_t)row;
                v = A[ar * lda + kb + kc];
            }
            As[r][kc] = v;
        }
        #pragma unroll
        for (int q = 0; q < 4; ++q) {
            int kr = (tid >> 6) + q * 4, cc = tid & 63;
            Bs[kr][cc] = Bm[(size_t)(kb + kr) * N + nb + cc];
        }
        __syncthreads();
        #pragma unroll
        for (int kk = 0; kk < 16; ++kk) {
            float a0 = As[ty * 4 + 0][kk], a1 = As[ty * 4 + 1][kk];
            float a2 = As[ty * 4 + 2][kk], a3 = As[ty * 4 + 3][kk];
            float4 b4 = *(const float4*)&Bs[kk][tx * 4];
            acc[0][0] += a0 * b4.x; acc[0][1] += a0 * b4.y; acc[0][2] += a0 * b4.z; acc[0][3] += a0 * b4.w;
            acc[1][0] += a1 * b4.x; acc[1][1] += a1 * b4.y; acc[1][2] += a1 * b4.z; acc[1][3] += a1 * b4.w;
            acc[2][0] += a2 * b4.x; acc[2][1] += a2 * b4.y; acc[2][2] += a2 * b4.z; acc[2][3] += a2 * b4.w;
            acc[3][0] += a3 * b4.x; acc[3][1] += a3 * b4.y; acc[3][2] += a3 * b4.z; acc[3][3] += a3 * b4.w;
        }
        __syncthreads();
    }
    #pragma unroll
    for (int i = 0; i < 4; ++i) {
        int row = rb + ty * 4 + i;
        if (row < M)
            #pragma unroll
            for (int j = 0; j < 4; ++j) {
                int col = nb + tx * 4 + j;
                C[(size_t)row * N + col] = fmaxf(acc[i][j] + bias[col], 0.f);
            }
    }
}

// ======================= concat + final head =======================
__global__ void concat_kernel(
    const int* __restrict__ idx_c, const int* __restrict__ idx_p,
    const float* __restrict__ comp_int, const float* __restrict__ Xc,
    const float* __restrict__ fd3, const float* __restrict__ prot_int,
    const float* __restrict__ Xp, const float* __restrict__ fp3,
    float* __restrict__ cat)
{
    int j = blockIdx.x * 256 + threadIdx.x;
    if (j >= BSZ * 384) return;
    int r = j / 384, c = j % 384;
    float v;
    if (c < 64)       v = comp_int[(size_t)idx_c[r] * 64 + c];
    else if (c < 128) v = Xc[(size_t)idx_c[r] * 64 + (c - 64)];
    else if (c < 192) v = fd3[(size_t)r * 64 + (c - 128)];
    else if (c < 256) v = prot_int[(size_t)idx_p[r] * 64 + (c - 192)];
    else if (c < 320) v = Xp[(size_t)idx_p[r] * 64 + (c - 256)];
    else              v = fp3[(size_t)r * 64 + (c - 320)];
    cat[j] = v;
}

__global__ void head_final(
    const float* __restrict__ h3, const float* __restrict__ W_int,
    const float* __restrict__ b_int, float* __restrict__ out)
{
    int r = blockIdx.x * 256 + threadIdx.x;
    if (r >= BSZ) return;
    float s0 = b_int[0], s1 = b_int[1];
    for (int k = 0; k < 256; ++k) {
        float h = h3[(size_t)r * 256 + k];
        s0 += h * W_int[k * 2 + 0];
        s1 += h * W_int[k * 2 + 1];
    }
    out[r * 2 + 0] = 1.f / (1.f + expf(-s0));
    out[r * 2 + 1] = 1.f / (1.f + expf(-s1));
}

// ======================= launch =======================
extern "C" void kernel_launch(void* const* d_in, const int* in_sizes, int n_in,
                              void* d_out, int out_size, void* d_ws, size_t ws_size,
                              hipStream_t stream)
{
    const int*   idx_c        = (const int*)  d_in[0];
    const int*   idx_p        = (const int*)  d_in[1];
    const int*   compounds    = (const int*)  d_in[2];
    const int*   proteins     = (const int*)  d_in[3];
    const float* adjacencies  = (const float*)d_in[4];
    const float* A_c          = (const float*)d_in[5];
    const float* A_p          = (const float*)d_in[6];
    const float* embed_fp     = (const float*)d_in[7];
    const float* embed_word   = (const float*)d_in[8];
    const float* Xs_c         = (const float*)d_in[9];
    const float* Xs_p         = (const float*)d_in[10];
    const float* drug_feat    = (const float*)d_in[11];
    const float* protein_feat = (const float*)d_in[12];
    const float* W_gnn        = (const float*)d_in[13];
    const float* b_gnn        = (const float*)d_in[14];
    const float* K_cnn        = (const float*)d_in[15];
    const float* b_cnn        = (const float*)d_in[16];
    const float* W_gcn_d      = (const float*)d_in[17];
    const float* b_gcn_d      = (const float*)d_in[18];
    const float* W_gcn_p      = (const float*)d_in[19];
    const float* b_gcn_p      = (const float*)d_in[20];
    const float* Wd1 = (const float*)d_in[21]; const float* bd1 = (const float*)d_in[22];
    const float* Wd2 = (const float*)d_in[23]; const float* bd2 = (const float*)d_in[24];
    const float* Wd3 = (const float*)d_in[25]; const float* bd3 = (const float*)d_in[26];
    const float* Wp1 = (const float*)d_in[27]; const float* bp1 = (const float*)d_in[28];
    const float* Wp2 = (const float*)d_in[29]; const float* bp2 = (const float*)d_in[30];
    const float* Wp3 = (const float*)d_in[31]; const float* bp3 = (const float*)d_in[32];
    const float* Wo1 = (const float*)d_in[33]; const float* bo1 = (const float*)d_in[34];
    const float* Wo2 = (const float*)d_in[35]; const float* bo2 = (const float*)d_in[36];
    const float* Wo3 = (const float*)d_in[37]; const float* bo3 = (const float*)d_in[38];
    const float* W_int = (const float*)d_in[39]; const float* b_int = (const float*)d_in[40];

    float* ws = (float*)d_ws;
    float* comp_int  = ws; ws += NC * 64;
    float* prot_part = ws; ws += NP * 16 * 64;
    float* prot_int  = ws; ws += NP * 64;
    float* wtab_g    = ws; ws += 8448;          // 3*11*512 halves = 33 KB
    float* gcn_part  = ws; ws += 8 * NC * 64;
    float* Xc_a = ws; ws += NC * 64;
    float* Xc_b = ws; ws += NC * 64;
    float* Xp_a = ws; ws += NP * 64;
    float* Xp_b = ws; ws += NP * 64;
    float* fd1 = ws; ws += BSZ * 128;
    float* fd2 = ws; ws += BSZ * 64;
    float* fd3 = ws; ws += BSZ * 64;
    float* fp1 = ws; ws += BSZ * 128;
    float* fp2 = ws; ws += BSZ * 64;
    float* fp3 = ws; ws += BSZ * 64;
    float* cat = ws; ws += BSZ * 384;
    float* h1  = ws; ws += BSZ * 256;
    float* h2m = ws; ws += BSZ * 256;
    float* h3  = ws; ws += BSZ * 256;
    (void)ws_size; (void)in_sizes; (void)n_in; (void)out_size;

    // branch 2 prep: band-weight table (one-time, tiny)
    cnn_wtab<<<66, 256, 0, stream>>>(K_cnn, (_Float16*)wtab_g);
    // branch 1: compound GNN
    gnn_kernel<<<NC, 320, 0, stream>>>(compounds, adjacencies, embed_fp, W_gnn, b_gnn, comp_int);
    // branch 2: protein CNN (banded MFMA, 32-row tiles)
    cnn_kernel<<<dim3(16, NP), 256, 0, stream>>>(proteins, embed_word, (const half8_t*)wtab_g, b_cnn, prot_part);
    cnn_reduce<<<NP, 64, 0, stream>>>(prot_part, prot_int);
    // branch 3: GCN drug
    spk_gemm64<<<dim3(32, 8), 256, 0, stream>>>(A_c, Xs_c, gcn_part, NC, 256);
    gcn_epi<<<32, 256, 0, stream>>>(gcn_part, 8, NC, W_gcn_d, b_gcn_d, Xc_a);
    spk_gemm64<<<dim3(32, 8), 256, 0, stream>>>(A_c, Xc_a, gcn_part, NC, 256);
    gcn_epi<<<32, 256, 0, stream>>>(gcn_part, 8, NC, W_gcn_d + 4096, b_gcn_d + 64, Xc_b);
    // branch 3b: GCN protein
    spk_gemm64<<<dim3(24, 8), 256, 0, stream>>>(A_p, Xs_p, gcn_part, NP, 192);
    gcn_epi<<<24, 256, 0, stream>>>(gcn_part, 8, NP, W_gcn_p, b_gcn_p, Xp_a);
    spk_gemm64<<<dim3(24, 8), 256, 0, stream>>>(A_p, Xp_a, gcn_part, NP, 192);
    gcn_epi<<<24, 256, 0, stream>>>(gcn_part, 8, NP, W_gcn_p + 4096, b_gcn_p + 64, Xp_b);
    // branch 4: drug MLP
    gemm_bias_relu<true ><<<dim3(64, 2), 256, 0, stream>>>(drug_feat, 1024, idx_c, Wd1, bd1, fd1, BSZ, 128, 1024);
    gemm_bias_relu<false><<<dim3(64, 1), 256, 0, stream>>>(fd1, 128, nullptr, Wd2, bd2, fd2, BSZ, 64, 128);
    gemm_bias_relu<false><<<dim3(64, 1), 256, 0, stream>>>(fd2, 64, nullptr, Wd3, bd3, fd3, BSZ, 64, 64);
    // branch 5: protein MLP
    gemm_bias_relu<true ><<<dim3(64, 2), 256, 0, stream>>>(protein_feat, 1024, idx_p, Wp1, bp1, fp1, BSZ, 128, 1024);
    gemm_bias_relu<false><<<dim3(64, 1), 256, 0, stream>>>(fp1, 128, nullptr, Wp2, bp2, fp2, BSZ, 64, 128);
    gemm_bias_relu<false><<<dim3(64, 1), 256, 0, stream>>>(fp2, 64, nullptr, Wp3, bp3, fp3, BSZ, 64, 64);
    // head
    concat_kernel<<<(BSZ * 384 + 255) / 256, 256, 0, stream>>>(idx_c, idx_p, comp_int, Xc_b, fd3, prot_int, Xp_b, fp3, cat);
    gemm_bias_relu<false><<<dim3(64, 4), 256, 0, stream>>>(cat, 384, nullptr, Wo1, bo1, h1, BSZ, 256, 384);
    gemm_bias_relu<false><<<dim3(64, 4), 256, 0, stream>>>(h1, 256, nullptr, Wo2, bo2, h2m, BSZ, 256, 256);
    gemm_bias_relu<false><<<dim3(64, 4), 256, 0, stream>>>(h2m, 256, nullptr, Wo3, bo3, h3, BSZ, 256, 256);
    head_final<<<(BSZ + 255) / 256, 256, 0, stream>>>(h3, W_int, b_int, (float*)d_out);
}

// Round 10
// 695.448 us; speedup vs baseline: 7.7133x; 1.4810x over previous
//
#include <hip/hip_runtime.h>
#include <math.h>

#define NC 2000
#define NP 1500
#define NA 40
#define LP 512
#define BSZ 4096
#define NW 8000

typedef _Float16 half8_t __attribute__((ext_vector_type(8)));
typedef float f32x4 __attribute__((ext_vector_type(4)));

// ======================= GNN (fused per compound) =======================
__global__ __launch_bounds__(320) void gnn_kernel(
    const int* __restrict__ compounds, const float* __restrict__ adjacencies,
    const float* __restrict__ embed_fp, const float* __restrict__ W_gnn,
    const float* __restrict__ b_gnn, float* __restrict__ comp_int)
{
    __shared__ float xs[40][68];
    __shared__ float hs[40][68];
    __shared__ float Ws[64][64];
    __shared__ float adjS[40][41];
    __shared__ float bS[64];
    const int n = blockIdx.x;
    const int tid = threadIdx.x;
    const int a = tid >> 3, g = tid & 7, cb = g * 8;

    for (int j = tid; j < 40 * 64; j += 320) {
        int r = j >> 6, c = j & 63;
        xs[r][c] = embed_fp[(size_t)compounds[n * NA + r] * 64 + c];
    }
    for (int j = tid; j < NA * NA; j += 320)
        adjS[j / NA][j % NA] = adjacencies[(size_t)n * (NA * NA) + j];

    for (int l = 0; l < 3; ++l) {
        __syncthreads();
        for (int j = tid; j < 4096; j += 320) Ws[j >> 6][j & 63] = W_gnn[l * 4096 + j];
        if (tid < 64) bS[tid] = b_gnn[l * 64 + tid];
        __syncthreads();
        float acc[8];
        #pragma unroll
        for (int j = 0; j < 8; ++j) acc[j] = bS[cb + j];
        #pragma unroll 8
        for (int d = 0; d < 64; ++d) {
            float x = xs[a][d];
            float4 w0 = *(const float4*)&Ws[d][cb];
            float4 w1 = *(const float4*)&Ws[d][cb + 4];
            acc[0] += x * w0.x; acc[1] += x * w0.y; acc[2] += x * w0.z; acc[3] += x * w0.w;
            acc[4] += x * w1.x; acc[5] += x * w1.y; acc[6] += x * w1.z; acc[7] += x * w1.w;
        }
        #pragma unroll
        for (int j = 0; j < 8; ++j) hs[a][cb + j] = fmaxf(acc[j], 0.f);
        __syncthreads();
        float4 x0 = *(float4*)&xs[a][cb];
        float4 x1 = *(float4*)&xs[a][cb + 4];
        #pragma unroll 8
        for (int b = 0; b < NA; ++b) {
            float ad = adjS[a][b];
            float4 h0 = *(const float4*)&hs[b][cb];
            float4 h1 = *(const float4*)&hs[b][cb + 4];
            x0.x += ad * h0.x; x0.y += ad * h0.y; x0.z += ad * h0.z; x0.w += ad * h0.w;
            x1.x += ad * h1.x; x1.y += ad * h1.y; x1.z += ad * h1.z; x1.w += ad * h1.w;
        }
        *(float4*)&xs[a][cb] = x0;
        *(float4*)&xs[a][cb + 4] = x1;
    }
    __syncthreads();
    if (tid < 64) {
        float s = 0.f;
        for (int r = 0; r < NA; ++r) s += xs[r][tid];
        comp_int[n * 64 + tid] = s * (1.0f / 40.0f);
    }
}

// ======================= CNN via MFMA (banded 16x16x32 f16) =======================
// Image LDS row-major 128 halves/row (256B), 16B-block XOR swizzle blk ^= row&7.
// Padded col pc = image col + 13; A-frag for strip c0 reads blocks B0..B0+3,
// B0=(c0+8)/8. Read-set: blocks 1..10. bufA: staged blocks 1..9 from ehp
// (zeros baked into 13-left/3-right pad); must-zero blk10.
// bufB: store_tile writes only pc in [13,77) -> must-zero blk1 (halves 8..12
// garbage otherwise - round-9 bug), blk9 (halves 77..79), blk10.
// Tiles: L1 r0={5,21,37,41} (rows 5..56), L2 r0={10,26,36} (10..51),
// L3 r0={15,31} (15..46 -> column sums). ehp rows: 80 halves, [13,77)=cols.

__device__ __forceinline__ int swz_off(int row, int half_col)
{
    int b = half_col >> 3;
    return row * 128 + (((b & 8) | ((b ^ row) & 7)) << 3) + (half_col & 7);
}

__global__ void embed_h(const float* __restrict__ ew, _Float16* __restrict__ ehp)
{
    int j = blockIdx.x * 256 + threadIdx.x;
    if (j >= NW * 80) return;
    int w = j / 80, h = j - w * 80;
    float v = (h >= 13 && h < 77) ? ew[w * 64 + (h - 13)] : 0.f;
    ehp[j] = (_Float16)v;
}

// wtab[L][dr][lane]: B-fragment (band matrix of K[L][dr][.]) per lane, 8 halves
__global__ void cnn_wtab(const float* __restrict__ K_cnn, _Float16* __restrict__ wtab)
{
    int h = blockIdx.x * 256 + threadIdx.x;
    if (h < 3 * 11 * 512) {
        int L = h / 5632, rem = h % 5632;
        int dr = rem >> 9, r2 = rem & 511, ln = r2 >> 3, i = r2 & 7;
        int dc = 8 * (ln >> 4) + i - (ln & 15);   // k - n
        float v = (dc >= 0 && dc < 11) ? K_cnn[L * 121 + dr * 11 + dc] : 0.f;
        wtab[h] = (_Float16)v;
    }
}

__global__ __launch_bounds__(256) void cnn_kernel(
    const int* __restrict__ proteins, const _Float16* __restrict__ ehp,
    const half8_t* __restrict__ wtab, const float* __restrict__ b_cnn,
    float* __restrict__ prot_part)
{
    __shared__ half8_t bufA8[62 * 16];
    __shared__ half8_t bufB8[62 * 16];
    _Float16* bufA = (_Float16*)bufA8;
    _Float16* bufB = (_Float16*)bufB8;

    const int tile = blockIdx.x, p = blockIdx.y;
    const int t0 = tile * 32, tid = threadIdx.x;
    const int lane = tid & 63, wid = tid >> 6;
    const int c0 = wid * 16;
    const int m = lane & 15, g = lane >> 4;

    half8_t z = {};
    // stage bufA blocks 1..9, rows rel [0,62) = global [t0-15, t0+47)
    for (int e = tid; e < 62 * 9; e += 256) {
        int i = e / 9, a = 1 + (e - 9 * i);
        int gr = t0 - 15 + i;
        half8_t v = z;
        if (gr >= 0 && gr < LP)
            v = *(const half8_t*)&ehp[(size_t)proteins[p * LP + gr] * 80 + 8 * a];
        *(half8_t*)&bufA[i * 128 + (((a & 8) | ((a ^ i) & 7)) << 3)] = v;
    }
    // zero read-but-never-stored blocks: bufA blk10; bufB blk1, blk9, blk10
    for (int e = tid; e < 62 * 4; e += 256) {
        int i = e >> 2, w = e & 3;
        if (w == 0)      bufA8[i * 16 + (8 | ((10 ^ i) & 7))] = z;   // bufA blk10
        else if (w == 1) bufB8[i * 16 + ((1 ^ i) & 7)] = z;          // bufB blk1
        else {
            int blk = 7 + w;                                          // 9 or 10
            bufB8[i * 16 + ((blk & 8) | ((blk ^ i) & 7))] = z;
        }
    }

    half8_t wf[11];
    auto load_wf = [&](int L) {
        #pragma unroll
        for (int dr = 0; dr < 11; ++dr) wf[dr] = wtab[L * 11 * 64 + dr * 64 + lane];
    };
    auto conv_tile = [&](const _Float16* src, int r0, float bias) -> f32x4 {
        f32x4 acc = {bias, bias, bias, bias};
        const int B0 = (c0 + 8) >> 3;
        #pragma unroll
        for (int dr = 0; dr < 11; ++dr) {
            int R = r0 - 5 + dr + m;
            int b = B0 + g;
            half8_t a = *(const half8_t*)&src[R * 128 + (((b & 8) | ((b ^ R) & 7)) << 3)];
            acc = __builtin_amdgcn_mfma_f32_16x16x32_f16(a, wf[dr], acc, 0, 0, 0);
        }
        return acc;
    };
    auto store_tile = [&](_Float16* dst, int r0, f32x4 acc) {
        int pc = c0 + 13 + m;
        #pragma unroll
        for (int j = 0; j < 4; ++j) {
            int row = r0 + 4 * g + j;
            int og = t0 - 15 + row;
            float v = fmaxf(acc[j], 0.f);
            dst[swz_off(row, pc)] = (_Float16)((og >= 0 && og < LP) ? v : 0.f);
        }
    };

    // ---- layer 1: bufA -> bufB
    load_wf(0);
    __syncthreads();
    {
        float b0 = b_cnn[0];
        const int r0s[4] = {5, 21, 37, 41};
        #pragma unroll
        for (int k = 0; k < 4; ++k) store_tile(bufB, r0s[k], conv_tile(bufA, r0s[k], b0));
    }
    __syncthreads();
    // ---- layer 2: bufB -> bufA
    load_wf(1);
    {
        float b1 = b_cnn[1];
        const int r0s[3] = {10, 26, 36};
        #pragma unroll
        for (int k = 0; k < 3; ++k) store_tile(bufA, r0s[k], conv_tile(bufB, r0s[k], b1));
    }
    __syncthreads();
    // ---- layer 3: bufA -> column sums over rows rel [15,47)
    load_wf(2);
    {
        float b2 = b_cnn[2];
        float cs = 0.f;
        const int r0s[2] = {15, 31};
        #pragma unroll
        for (int k = 0; k < 2; ++k) {
            f32x4 acc = conv_tile(bufA, r0s[k], b2);
            #pragma unroll
            for (int j = 0; j < 4; ++j) cs += fmaxf(acc[j], 0.f);
        }
        cs += __shfl_xor(cs, 16, 64);
        cs += __shfl_xor(cs, 32, 64);
        if (lane < 16)
            prot_part[((size_t)p * 16 + tile) * 64 + c0 + lane] = cs;
    }
}

__global__ void cnn_reduce(const float* __restrict__ prot_part, float* __restrict__ prot_int)
{
    const int p = blockIdx.x, c = threadIdx.x;
    float s = 0.f;
    for (int t = 0; t < 16; ++t) s += prot_part[((size_t)p * 16 + t) * 64 + c];
    prot_int[p * 64 + c] = s * (1.0f / 512.0f);
}

// ======================= GCN: split-K GEMM (N=64) + epilogue =======================
__global__ __launch_bounds__(256) void spk_gemm64(
    const float* __restrict__ A, const float* __restrict__ X,
    float* __restrict__ part, int M, int kchunk)
{
    __shared__ float As[64][17];
    __shared__ float Xs[16][64];
    const int rb = blockIdx.x * 64;
    const int s = blockIdx.y;
    const int k0 = s * kchunk;
    const int k1 = (k0 + kchunk < M) ? (k0 + kchunk) : M;
    const int tid = threadIdx.x, tx = tid & 15, ty = tid >> 4;
    float acc[4][4] = {};
    for (int kb = k0; kb < k1; kb += 16) {
        #pragma unroll
        for (int q = 0; q < 4; ++q) {
            int r = (tid >> 4) + q * 16, kc = tid & 15;
            int row = rb + r, kidx = kb + kc;
            As[r][kc] = (row < M && kidx < k1) ? A[(size_t)row * M + kidx] : 0.f;
        }
        #pragma unroll
        for (int q = 0; q < 4; ++q) {
            int kr = (tid >> 6) + q * 4, cc = tid & 63;
            int kidx = kb + kr;
            Xs[kr][cc] = (kidx < k1) ? X[(size_t)kidx * 64 + cc] : 0.f;
        }
        __syncthreads();
        #pragma unroll
        for (int kk = 0; kk < 16; ++kk) {
            float a0 = As[ty * 4 + 0][kk], a1 = As[ty * 4 + 1][kk];
            float a2 = As[ty * 4 + 2][kk], a3 = As[ty * 4 + 3][kk];
            float4 b4 = *(const float4*)&Xs[kk][tx * 4];
            acc[0][0] += a0 * b4.x; acc[0][1] += a0 * b4.y; acc[0][2] += a0 * b4.z; acc[0][3] += a0 * b4.w;
            acc[1][0] += a1 * b4.x; acc[1][1] += a1 * b4.y; acc[1][2] += a1 * b4.z; acc[1][3] += a1 * b4.w;
            acc[2][0] += a2 * b4.x; acc[2][1] += a2 * b4.y; acc[2][2] += a2 * b4.z; acc[2][3] += a2 * b4.w;
            acc[3][0] += a3 * b4.x; acc[3][1] += a3 * b4.y; acc[3][2] += a3 * b4.z; acc[3][3] += a3 * b4.w;
        }
        __syncthreads();
    }
    #pragma unroll
    for (int i = 0; i < 4; ++i) {
        int row = rb + ty * 4 + i;
        if (row < M)
            *(float4*)&part[((size_t)s * M + row) * 64 + tx * 4] =
                make_float4(acc[i][0], acc[i][1], acc[i][2], acc[i][3]);
    }
}

__global__ __launch_bounds__(256) void gcn_epi(
    const float* __restrict__ part, int S, int M,
    const float* __restrict__ W, const float* __restrict__ bias,
    float* __restrict__ Xout)
{
    __shared__ float Ys[64][68];
    __shared__ float Ws[64][64];
    const int rb = blockIdx.x * 64;
    const int tid = threadIdx.x;
    for (int j = tid; j < 4096; j += 256) Ws[j >> 6][j & 63] = W[j];
    for (int j = tid; j < 4096; j += 256) {
        int r = j >> 6, c = j & 63;
        float sum = 0.f;
        if (rb + r < M)
            for (int t = 0; t < S; ++t) sum += part[((size_t)t * M + rb + r) * 64 + c];
        Ys[r][c] = sum;
    }
    __syncthreads();
    const int tx = tid & 15, ty = tid >> 4;
    float acc[4][4];
    #pragma unroll
    for (int i = 0; i < 4; ++i)
        #pragma unroll
        for (int j = 0; j < 4; ++j) acc[i][j] = bias[tx * 4 + j];
    for (int d = 0; d < 64; ++d) {
        float a0 = Ys[ty * 4 + 0][d], a1 = Ys[ty * 4 + 1][d];
        float a2 = Ys[ty * 4 + 2][d], a3 = Ys[ty * 4 + 3][d];
        float4 w4 = *(const float4*)&Ws[d][tx * 4];
        acc[0][0] += a0 * w4.x; acc[0][1] += a0 * w4.y; acc[0][2] += a0 * w4.z; acc[0][3] += a0 * w4.w;
        acc[1][0] += a1 * w4.x; acc[1][1] += a1 * w4.y; acc[1][2] += a1 * w4.z; acc[1][3] += a1 * w4.w;
        acc[2][0] += a2 * w4.x; acc[2][1] += a2 * w4.y; acc[2][2] += a2 * w4.z; acc[2][3] += a2 * w4.w;
        acc[3][0] += a3 * w4.x; acc[3][1] += a3 * w4.y; acc[3][2] += a3 * w4.z; acc[3][3] += a3 * w4.w;
    }
    #pragma unroll
    for (int i = 0; i < 4; ++i) {
        int row = rb + ty * 4 + i;
        if (row < M)
            #pragma unroll
            for (int j = 0; j < 4; ++j)
                Xout[(size_t)row * 64 + tx * 4 + j] = fmaxf(acc[i][j], 0.f);
    }
}

// ===== generic GEMM + bias + relu, BM=32/BK=32 (M mult of 32; N mult of 64)
template<bool GATHER>
__global__ __launch_bounds__(256) void gemm_bias_relu(
    const float* __restrict__ A, int lda, const int* __restrict__ idx,
    const float* __restrict__ Bm, const float* __restrict__ bias,
    float* __restrict__ C, int M, int N, int K)
{
    __shared__ float As[32][33];
    __shared__ float Bs[32][64];
    const int rb = blockIdx.x * 32, nb = blockIdx.y * 64;
    const int tid = threadIdx.x, tx = tid & 15, ty = tid >> 4;
    float acc[2][4] = {};
    for (int kb = 0; kb < K; kb += 32) {
        #pragma unroll
        for (int q = 0; q < 4; ++q) {
            int r = (tid >> 5) + q * 8, kc = tid & 31;
            size_t ar = GATHER ? (size_t)idx[rb + r] : (size_t)(rb + r);
            As[r][kc] = A[ar * lda + kb + kc];
        }
        #pragma unroll
        for (int q = 0; q < 8; ++q) {
            int kr = (tid >> 6) + q * 4, cc = tid & 63;
            Bs[kr][cc] = Bm[(size_t)(kb + kr) * N + nb + cc];
        }
        __syncthreads();
        #pragma unroll
        for (int kk = 0; kk < 32; ++kk) {
            float a0 = As[ty * 2 + 0][kk], a1 = As[ty * 2 + 1][kk];
            float4 b4 = *(const float4*)&Bs[kk][tx * 4];
            acc[0][0] += a0 * b4.x; acc[0][1] += a0 * b4.y; acc[0][2] += a0 * b4.z; acc[0][3] += a0 * b4.w;
            acc[1][0] += a1 * b4.x; acc[1][1] += a1 * b4.y; acc[1][2] += a1 * b4.z; acc[1][3] += a1 * b4.w;
        }
        __syncthreads();
    }
    #pragma unroll
    for (int i = 0; i < 2; ++i) {
        int row = rb + ty * 2 + i;
        #pragma unroll
        for (int j = 0; j < 4; ++j) {
            int col = nb + tx * 4 + j;
            C[(size_t)row * N + col] = fmaxf(acc[i][j] + bias[col], 0.f);
        }
    }
}

// ======================= concat + final head =======================
__global__ void concat_kernel(
    const int* __restrict__ idx_c, const int* __restrict__ idx_p,
    const float* __restrict__ comp_int, const float* __restrict__ Xc,
    const float* __restrict__ fd3, const float* __restrict__ prot_int,
    const float* __restrict__ Xp, const float* __restrict__ fp3,
    float* __restrict__ cat)
{
    int j = blockIdx.x * 256 + threadIdx.x;
    if (j >= BSZ * 384) return;
    int r = j / 384, c = j % 384;
    float v;
    if (c < 64)       v = comp_int[(size_t)idx_c[r] * 64 + c];
    else if (c < 128) v = Xc[(size_t)idx_c[r] * 64 + (c - 64)];
    else if (c < 192) v = fd3[(size_t)r * 64 + (c - 128)];
    else if (c < 256) v = prot_int[(size_t)idx_p[r] * 64 + (c - 192)];
    else if (c < 320) v = Xp[(size_t)idx_p[r] * 64 + (c - 256)];
    else              v = fp3[(size_t)r * 64 + (c - 320)];
    cat[j] = v;
}

__global__ void head_final(
    const float* __restrict__ h3, const float* __restrict__ W_int,
    const float* __restrict__ b_int, float* __restrict__ out)
{
    int r = blockIdx.x * 256 + threadIdx.x;
    if (r >= BSZ) return;
    float s0 = b_int[0], s1 = b_int[1];
    for (int k = 0; k < 256; ++k) {
        float h = h3[(size_t)r * 256 + k];
        s0 += h * W_int[k * 2 + 0];
        s1 += h * W_int[k * 2 + 1];
    }
    out[r * 2 + 0] = 1.f / (1.f + expf(-s0));
    out[r * 2 + 1] = 1.f / (1.f + expf(-s1));
}

// ======================= launch =======================
extern "C" void kernel_launch(void* const* d_in, const int* in_sizes, int n_in,
                              void* d_out, int out_size, void* d_ws, size_t ws_size,
                              hipStream_t stream)
{
    const int*   idx_c        = (const int*)  d_in[0];
    const int*   idx_p        = (const int*)  d_in[1];
    const int*   compounds    = (const int*)  d_in[2];
    const int*   proteins     = (const int*)  d_in[3];
    const float* adjacencies  = (const float*)d_in[4];
    const float* A_c          = (const float*)d_in[5];
    const float* A_p          = (const float*)d_in[6];
    const float* embed_fp     = (const float*)d_in[7];
    const float* embed_word   = (const float*)d_in[8];
    const float* Xs_c         = (const float*)d_in[9];
    const float* Xs_p         = (const float*)d_in[10];
    const float* drug_feat    = (const float*)d_in[11];
    const float* protein_feat = (const float*)d_in[12];
    const float* W_gnn        = (const float*)d_in[13];
    const float* b_gnn        = (const float*)d_in[14];
    const float* K_cnn        = (const float*)d_in[15];
    const float* b_cnn        = (const float*)d_in[16];
    const float* W_gcn_d      = (const float*)d_in[17];
    const float* b_gcn_d      = (const float*)d_in[18];
    const float* W_gcn_p      = (const float*)d_in[19];
    const float* b_gcn_p      = (const float*)d_in[20];
    const float* Wd1 = (const float*)d_in[21]; const float* bd1 = (const float*)d_in[22];
    const float* Wd2 = (const float*)d_in[23]; const float* bd2 = (const float*)d_in[24];
    const float* Wd3 = (const float*)d_in[25]; const float* bd3 = (const float*)d_in[26];
    const float* Wp1 = (const float*)d_in[27]; const float* bp1 = (const float*)d_in[28];
    const float* Wp2 = (const float*)d_in[29]; const float* bp2 = (const float*)d_in[30];
    const float* Wp3 = (const float*)d_in[31]; const float* bp3 = (const float*)d_in[32];
    const float* Wo1 = (const float*)d_in[33]; const float* bo1 = (const float*)d_in[34];
    const float* Wo2 = (const float*)d_in[35]; const float* bo2 = (const float*)d_in[36];
    const float* Wo3 = (const float*)d_in[37]; const float* bo3 = (const float*)d_in[38];
    const float* W_int = (const float*)d_in[39]; const float* b_int = (const float*)d_in[40];

    float* ws = (float*)d_ws;
    float* comp_int  = ws; ws += NC * 64;
    float* prot_part = ws; ws += NP * 16 * 64;
    float* prot_int  = ws; ws += NP * 64;
    float* wtab_g    = ws; ws += 8448;          // 3*11*512 halves
    float* ehp_g     = ws; ws += NW * 40;       // 8000 x 80 halves (padded fp16 embed)
    float* gcn_part  = ws; ws += 8 * NC * 64;
    float* Xc_a = ws; ws += NC * 64;
    float* Xc_b = ws; ws += NC * 64;
    float* Xp_a = ws; ws += NP * 64;
    float* Xp_b = ws; ws += NP * 64;
    float* fd1 = ws; ws += BSZ * 128;
    float* fd2 = ws; ws += BSZ * 64;
    float* fd3 = ws; ws += BSZ * 64;
    float* fp1 = ws; ws += BSZ * 128;
    float* fp2 = ws; ws += BSZ * 64;
    float* fp3 = ws; ws += BSZ * 64;
    float* cat = ws; ws += BSZ * 384;
    float* h1  = ws; ws += BSZ * 256;
    float* h2m = ws; ws += BSZ * 256;
    float* h3  = ws; ws += BSZ * 256;
    (void)ws_size; (void)in_sizes; (void)n_in; (void)out_size;

    // branch 2 prep: band-weight table + padded fp16 embedding (one-time)
    cnn_wtab<<<66, 256, 0, stream>>>(K_cnn, (_Float16*)wtab_g);
    embed_h<<<(NW * 80 + 255) / 256, 256, 0, stream>>>(embed_word, (_Float16*)ehp_g);
    // branch 1: compound GNN
    gnn_kernel<<<NC, 320, 0, stream>>>(compounds, adjacencies, embed_fp, W_gnn, b_gnn, comp_int);
    // branch 2: protein CNN (banded MFMA, 32-row tiles)
    cnn_kernel<<<dim3(16, NP), 256, 0, stream>>>(proteins, (const _Float16*)ehp_g, (const half8_t*)wtab_g, b_cnn, prot_part);
    cnn_reduce<<<NP, 64, 0, stream>>>(prot_part, prot_int);
    // branch 3: GCN drug
    spk_gemm64<<<dim3(32, 8), 256, 0, stream>>>(A_c, Xs_c, gcn_part, NC, 256);
    gcn_epi<<<32, 256, 0, stream>>>(gcn_part, 8, NC, W_gcn_d, b_gcn_d, Xc_a);
    spk_gemm64<<<dim3(32, 8), 256, 0, stream>>>(A_c, Xc_a, gcn_part, NC, 256);
    gcn_epi<<<32, 256, 0, stream>>>(gcn_part, 8, NC, W_gcn_d + 4096, b_gcn_d + 64, Xc_b);
    // branch 3b: GCN protein
    spk_gemm64<<<dim3(24, 8), 256, 0, stream>>>(A_p, Xs_p, gcn_part, NP, 192);
    gcn_epi<<<24, 256, 0, stream>>>(gcn_part, 8, NP, W_gcn_p, b_gcn_p, Xp_a);
    spk_gemm64<<<dim3(24, 8), 256, 0, stream>>>(A_p, Xp_a, gcn_part, NP, 192);
    gcn_epi<<<24, 256, 0, stream>>>(gcn_part, 8, NP, W_gcn_p + 4096, b_gcn_p + 64, Xp_b);
    // branch 4: drug MLP
    gemm_bias_relu<true ><<<dim3(128, 2), 256, 0, stream>>>(drug_feat, 1024, idx_c, Wd1, bd1, fd1, BSZ, 128, 1024);
    gemm_bias_relu<false><<<dim3(128, 1), 256, 0, stream>>>(fd1, 128, nullptr, Wd2, bd2, fd2, BSZ, 64, 128);
    gemm_bias_relu<false><<<dim3(128, 1), 256, 0, stream>>>(fd2, 64, nullptr, Wd3, bd3, fd3, BSZ, 64, 64);
    // branch 5: protein MLP
    gemm_bias_relu<true ><<<dim3(128, 2), 256, 0, stream>>>(protein_feat, 1024, idx_p, Wp1, bp1, fp1, BSZ, 128, 1024);
    gemm_bias_relu<false><<<dim3(128, 1), 256, 0, stream>>>(fp1, 128, nullptr, Wp2, bp2, fp2, BSZ, 64, 128);
    gemm_bias_relu<false><<<dim3(128, 1), 256, 0, stream>>>(fp2, 64, nullptr, Wp3, bp3, fp3, BSZ, 64, 64);
    // head
    concat_kernel<<<(BSZ * 384 + 255) / 256, 256, 0, stream>>>(idx_c, idx_p, comp_int, Xc_b, fd3, prot_int, Xp_b, fp3, cat);
    gemm_bias_relu<false><<<dim3(128, 4), 256, 0, stream>>>(cat, 384, nullptr, Wo1, bo1, h1, BSZ, 256, 384);
    gemm_bias_relu<false><<<dim3(128, 4), 256, 0, stream>>>(h1, 256, nullptr, Wo2, bo2, h2m, BSZ, 256, 256);
    gemm_bias_relu<false><<<dim3(128, 4), 256, 0, stream>>>(h2m, 256, nullptr, Wo3, bo3, h3, BSZ, 256, 256);
    head_final<<<(BSZ + 255) / 256, 256, 0, stream>>>(h3, W_int, b_int, (float*)d_out);
}

// Round 11
// 541.098 us; speedup vs baseline: 9.9136x; 1.2853x over previous
//
#include <hip/hip_runtime.h>
#include <math.h>

#define NC 2000
#define NP 1500
#define NA 40
#define LP 512
#define BSZ 4096
#define NW 8000

typedef _Float16 half8_t __attribute__((ext_vector_type(8)));
typedef float f32x4 __attribute__((ext_vector_type(4)));

// ======================= GNN (fused per compound) =======================
__global__ __launch_bounds__(320) void gnn_kernel(
    const int* __restrict__ compounds, const float* __restrict__ adjacencies,
    const float* __restrict__ embed_fp, const float* __restrict__ W_gnn,
    const float* __restrict__ b_gnn, float* __restrict__ comp_int)
{
    __shared__ float xs[40][68];
    __shared__ float hs[40][68];
    __shared__ float Ws[64][64];
    __shared__ float adjS[40][41];
    __shared__ float bS[64];
    const int n = blockIdx.x;
    const int tid = threadIdx.x;
    const int a = tid >> 3, g = tid & 7, cb = g * 8;

    for (int j = tid; j < 40 * 64; j += 320) {
        int r = j >> 6, c = j & 63;
        xs[r][c] = embed_fp[(size_t)compounds[n * NA + r] * 64 + c];
    }
    for (int j = tid; j < NA * NA; j += 320)
        adjS[j / NA][j % NA] = adjacencies[(size_t)n * (NA * NA) + j];

    for (int l = 0; l < 3; ++l) {
        __syncthreads();
        for (int j = tid; j < 4096; j += 320) Ws[j >> 6][j & 63] = W_gnn[l * 4096 + j];
        if (tid < 64) bS[tid] = b_gnn[l * 64 + tid];
        __syncthreads();
        float acc[8];
        #pragma unroll
        for (int j = 0; j < 8; ++j) acc[j] = bS[cb + j];
        #pragma unroll 8
        for (int d = 0; d < 64; ++d) {
            float x = xs[a][d];
            float4 w0 = *(const float4*)&Ws[d][cb];
            float4 w1 = *(const float4*)&Ws[d][cb + 4];
            acc[0] += x * w0.x; acc[1] += x * w0.y; acc[2] += x * w0.z; acc[3] += x * w0.w;
            acc[4] += x * w1.x; acc[5] += x * w1.y; acc[6] += x * w1.z; acc[7] += x * w1.w;
        }
        #pragma unroll
        for (int j = 0; j < 8; ++j) hs[a][cb + j] = fmaxf(acc[j], 0.f);
        __syncthreads();
        float4 x0 = *(float4*)&xs[a][cb];
        float4 x1 = *(float4*)&xs[a][cb + 4];
        #pragma unroll 8
        for (int b = 0; b < NA; ++b) {
            float ad = adjS[a][b];
            float4 h0 = *(const float4*)&hs[b][cb];
            float4 h1 = *(const float4*)&hs[b][cb + 4];
            x0.x += ad * h0.x; x0.y += ad * h0.y; x0.z += ad * h0.z; x0.w += ad * h0.w;
            x1.x += ad * h1.x; x1.y += ad * h1.y; x1.z += ad * h1.z; x1.w += ad * h1.w;
        }
        *(float4*)&xs[a][cb] = x0;
        *(float4*)&xs[a][cb + 4] = x1;
    }
    __syncthreads();
    if (tid < 64) {
        float s = 0.f;
        for (int r = 0; r < NA; ++r) s += xs[r][tid];
        comp_int[n * 64 + tid] = s * (1.0f / 40.0f);
    }
}

// ======================= CNN via MFMA (banded 16x16x32 f16) =======================
// (layout/tiling notes as round-10; bufB blk1 zero-init bug fixed there)
__device__ __forceinline__ int swz_off(int row, int half_col)
{
    int b = half_col >> 3;
    return row * 128 + (((b & 8) | ((b ^ row) & 7)) << 3) + (half_col & 7);
}

// fused one-time prep: wtab (3*11*512 halves) then padded fp16 embed (NW*80)
__global__ void cnn_prep(const float* __restrict__ K_cnn, _Float16* __restrict__ wtab,
                         const float* __restrict__ ew, _Float16* __restrict__ ehp)
{
    int j = blockIdx.x * 256 + threadIdx.x;
    if (j < 16896) {
        int L = j / 5632, rem = j % 5632;
        int dr = rem >> 9, r2 = rem & 511, ln = r2 >> 3, i = r2 & 7;
        int dc = 8 * (ln >> 4) + i - (ln & 15);   // k - n
        float v = (dc >= 0 && dc < 11) ? K_cnn[L * 121 + dr * 11 + dc] : 0.f;
        wtab[j] = (_Float16)v;
        return;
    }
    int e = j - 16896;
    if (e >= NW * 80) return;
    int w = e / 80, h = e - w * 80;
    float v = (h >= 13 && h < 77) ? ew[w * 64 + (h - 13)] : 0.f;
    ehp[e] = (_Float16)v;
}

__global__ __launch_bounds__(256) void cnn_kernel(
    const int* __restrict__ proteins, const _Float16* __restrict__ ehp,
    const half8_t* __restrict__ wtab, const float* __restrict__ b_cnn,
    float* __restrict__ prot_part)
{
    __shared__ half8_t bufA8[62 * 16];
    __shared__ half8_t bufB8[62 * 16];
    _Float16* bufA = (_Float16*)bufA8;
    _Float16* bufB = (_Float16*)bufB8;

    const int tile = blockIdx.x, p = blockIdx.y;
    const int t0 = tile * 32, tid = threadIdx.x;
    const int lane = tid & 63, wid = tid >> 6;
    const int c0 = wid * 16;
    const int m = lane & 15, g = lane >> 4;

    half8_t z = {};
    for (int e = tid; e < 62 * 9; e += 256) {
        int i = e / 9, a = 1 + (e - 9 * i);
        int gr = t0 - 15 + i;
        half8_t v = z;
        if (gr >= 0 && gr < LP)
            v = *(const half8_t*)&ehp[(size_t)proteins[p * LP + gr] * 80 + 8 * a];
        *(half8_t*)&bufA[i * 128 + (((a & 8) | ((a ^ i) & 7)) << 3)] = v;
    }
    // zero read-but-never-stored blocks: bufA blk10; bufB blk1, blk9, blk10
    for (int e = tid; e < 62 * 4; e += 256) {
        int i = e >> 2, w = e & 3;
        if (w == 0)      bufA8[i * 16 + (8 | ((10 ^ i) & 7))] = z;
        else if (w == 1) bufB8[i * 16 + ((1 ^ i) & 7)] = z;
        else {
            int blk = 7 + w;
            bufB8[i * 16 + ((blk & 8) | ((blk ^ i) & 7))] = z;
        }
    }

    half8_t wf[11];
    auto load_wf = [&](int L) {
        #pragma unroll
        for (int dr = 0; dr < 11; ++dr) wf[dr] = wtab[L * 11 * 64 + dr * 64 + lane];
    };
    auto conv_tile = [&](const _Float16* src, int r0, float bias) -> f32x4 {
        f32x4 acc = {bias, bias, bias, bias};
        const int B0 = (c0 + 8) >> 3;
        #pragma unroll
        for (int dr = 0; dr < 11; ++dr) {
            int R = r0 - 5 + dr + m;
            int b = B0 + g;
            half8_t a = *(const half8_t*)&src[R * 128 + (((b & 8) | ((b ^ R) & 7)) << 3)];
            acc = __builtin_amdgcn_mfma_f32_16x16x32_f16(a, wf[dr], acc, 0, 0, 0);
        }
        return acc;
    };
    auto store_tile = [&](_Float16* dst, int r0, f32x4 acc) {
        int pc = c0 + 13 + m;
        #pragma unroll
        for (int j = 0; j < 4; ++j) {
            int row = r0 + 4 * g + j;
            int og = t0 - 15 + row;
            float v = fmaxf(acc[j], 0.f);
            dst[swz_off(row, pc)] = (_Float16)((og >= 0 && og < LP) ? v : 0.f);
        }
    };

    load_wf(0);
    __syncthreads();
    {
        float b0 = b_cnn[0];
        const int r0s[4] = {5, 21, 37, 41};
        #pragma unroll
        for (int k = 0; k < 4; ++k) store_tile(bufB, r0s[k], conv_tile(bufA, r0s[k], b0));
    }
    __syncthreads();
    load_wf(1);
    {
        float b1 = b_cnn[1];
        const int r0s[3] = {10, 26, 36};
        #pragma unroll
        for (int k = 0; k < 3; ++k) store_tile(bufA, r0s[k], conv_tile(bufB, r0s[k], b1));
    }
    __syncthreads();
    load_wf(2);
    {
        float b2 = b_cnn[2];
        float cs = 0.f;
        const int r0s[2] = {15, 31};
        #pragma unroll
        for (int k = 0; k < 2; ++k) {
            f32x4 acc = conv_tile(bufA, r0s[k], b2);
            #pragma unroll
            for (int j = 0; j < 4; ++j) cs += fmaxf(acc[j], 0.f);
        }
        cs += __shfl_xor(cs, 16, 64);
        cs += __shfl_xor(cs, 32, 64);
        if (lane < 16)
            prot_part[((size_t)p * 16 + tile) * 64 + c0 + lane] = cs;
    }
}

__global__ void cnn_reduce(const float* __restrict__ prot_part, float* __restrict__ prot_int)
{
    const int p = blockIdx.x, c = threadIdx.x;
    float s = 0.f;
    for (int t = 0; t < 16; ++t) s += prot_part[((size_t)p * 16 + t) * 64 + c];
    prot_int[p * 64 + c] = s * (1.0f / 512.0f);
}

// ======== GCN: dual split-K GEMM (drug z=0, protein z=1) + dual epilogue ========
__global__ __launch_bounds__(256) void spk_gemm64_dual(
    const float* __restrict__ A0, const float* __restrict__ X0, float* __restrict__ P0, int M0, int kc0,
    const float* __restrict__ A1, const float* __restrict__ X1, float* __restrict__ P1, int M1, int kc1, int nx1)
{
    const float* A; const float* X; float* part; int M, kchunk;
    if (blockIdx.z == 0) { A = A0; X = X0; part = P0; M = M0; kchunk = kc0; }
    else { if ((int)blockIdx.x >= nx1) return; A = A1; X = X1; part = P1; M = M1; kchunk = kc1; }

    __shared__ float As[64][17];
    __shared__ float Xs[16][64];
    const int rb = blockIdx.x * 64;
    const int s = blockIdx.y;
    const int k0 = s * kchunk;
    const int k1 = (k0 + kchunk < M) ? (k0 + kchunk) : M;
    const int tid = threadIdx.x, tx = tid & 15, ty = tid >> 4;
    float acc[4][4] = {};
    for (int kb = k0; kb < k1; kb += 16) {
        #pragma unroll
        for (int q = 0; q < 4; ++q) {
            int r = (tid >> 4) + q * 16, kc = tid & 15;
            int row = rb + r, kidx = kb + kc;
            As[r][kc] = (row < M && kidx < k1) ? A[(size_t)row * M + kidx] : 0.f;
        }
        #pragma unroll
        for (int q = 0; q < 4; ++q) {
            int kr = (tid >> 6) + q * 4, cc = tid & 63;
            int kidx = kb + kr;
            Xs[kr][cc] = (kidx < k1) ? X[(size_t)kidx * 64 + cc] : 0.f;
        }
        __syncthreads();
        #pragma unroll
        for (int kk = 0; kk < 16; ++kk) {
            float a0 = As[ty * 4 + 0][kk], a1 = As[ty * 4 + 1][kk];
            float a2 = As[ty * 4 + 2][kk], a3 = As[ty * 4 + 3][kk];
            float4 b4 = *(const float4*)&Xs[kk][tx * 4];
            acc[0][0] += a0 * b4.x; acc[0][1] += a0 * b4.y; acc[0][2] += a0 * b4.z; acc[0][3] += a0 * b4.w;
            acc[1][0] += a1 * b4.x; acc[1][1] += a1 * b4.y; acc[1][2] += a1 * b4.z; acc[1][3] += a1 * b4.w;
            acc[2][0] += a2 * b4.x; acc[2][1] += a2 * b4.y; acc[2][2] += a2 * b4.z; acc[2][3] += a2 * b4.w;
            acc[3][0] += a3 * b4.x; acc[3][1] += a3 * b4.y; acc[3][2] += a3 * b4.z; acc[3][3] += a3 * b4.w;
        }
        __syncthreads();
    }
    #pragma unroll
    for (int i = 0; i < 4; ++i) {
        int row = rb + ty * 4 + i;
        if (row < M)
            *(float4*)&part[((size_t)s * M + row) * 64 + tx * 4] =
                make_float4(acc[i][0], acc[i][1], acc[i][2], acc[i][3]);
    }
}

__global__ __launch_bounds__(256) void gcn_epi_dual(
    const float* __restrict__ P0, int M0, const float* __restrict__ W0, const float* __restrict__ b0, float* __restrict__ O0,
    const float* __restrict__ P1, int M1, const float* __restrict__ W1, const float* __restrict__ b1, float* __restrict__ O1,
    int nx1)
{
    const float* part; const float* W; const float* bias; float* Xout; int M;
    if (blockIdx.z == 0) { part = P0; W = W0; bias = b0; Xout = O0; M = M0; }
    else { if ((int)blockIdx.x >= nx1) return; part = P1; W = W1; bias = b1; Xout = O1; M = M1; }

    __shared__ float Ys[64][68];
    __shared__ float Ws[64][64];
    const int rb = blockIdx.x * 64;
    const int tid = threadIdx.x;
    for (int j = tid; j < 4096; j += 256) Ws[j >> 6][j & 63] = W[j];
    for (int j = tid; j < 4096; j += 256) {
        int r = j >> 6, c = j & 63;
        float sum = 0.f;
        if (rb + r < M)
            for (int t = 0; t < 8; ++t) sum += part[((size_t)t * M + rb + r) * 64 + c];
        Ys[r][c] = sum;
    }
    __syncthreads();
    const int tx = tid & 15, ty = tid >> 4;
    float acc[4][4];
    #pragma unroll
    for (int i = 0; i < 4; ++i)
        #pragma unroll
        for (int j = 0; j < 4; ++j) acc[i][j] = bias[tx * 4 + j];
    for (int d = 0; d < 64; ++d) {
        float a0 = Ys[ty * 4 + 0][d], a1 = Ys[ty * 4 + 1][d];
        float a2 = Ys[ty * 4 + 2][d], a3 = Ys[ty * 4 + 3][d];
        float4 w4 = *(const float4*)&Ws[d][tx * 4];
        acc[0][0] += a0 * w4.x; acc[0][1] += a0 * w4.y; acc[0][2] += a0 * w4.z; acc[0][3] += a0 * w4.w;
        acc[1][0] += a1 * w4.x; acc[1][1] += a1 * w4.y; acc[1][2] += a1 * w4.z; acc[1][3] += a1 * w4.w;
        acc[2][0] += a2 * w4.x; acc[2][1] += a2 * w4.y; acc[2][2] += a2 * w4.z; acc[2][3] += a2 * w4.w;
        acc[3][0] += a3 * w4.x; acc[3][1] += a3 * w4.y; acc[3][2] += a3 * w4.z; acc[3][3] += a3 * w4.w;
    }
    #pragma unroll
    for (int i = 0; i < 4; ++i) {
        int row = rb + ty * 4 + i;
        if (row < M)
            #pragma unroll
            for (int j = 0; j < 4; ++j)
                Xout[(size_t)row * 64 + tx * 4 + j] = fmaxf(acc[i][j], 0.f);
    }
}

// ===== dual GEMM + bias + relu, BM=32/BK=32 (drug z=0 / protein z=1) =====
template<bool GATHER>
__global__ __launch_bounds__(256) void gemm_br_dual(
    const float* __restrict__ A0, const int* __restrict__ idx0,
    const float* __restrict__ B0, const float* __restrict__ bias0, float* __restrict__ C0,
    const float* __restrict__ A1, const int* __restrict__ idx1,
    const float* __restrict__ B1, const float* __restrict__ bias1, float* __restrict__ C1,
    int lda, int N, int K)
{
    const float* A; const int* idx; const float* Bm; const float* bias; float* C;
    if (blockIdx.z == 0) { A = A0; idx = idx0; Bm = B0; bias = bias0; C = C0; }
    else                 { A = A1; idx = idx1; Bm = B1; bias = bias1; C = C1; }

    __shared__ float As[32][33];
    __shared__ float Bs[32][64];
    const int rb = blockIdx.x * 32, nb = blockIdx.y * 64;
    const int tid = threadIdx.x, tx = tid & 15, ty = tid >> 4;
    float acc[2][4] = {};
    for (int kb = 0; kb < K; kb += 32) {
        #pragma unroll
        for (int q = 0; q < 4; ++q) {
            int r = (tid >> 5) + q * 8, kc = tid & 31;
            size_t ar = GATHER ? (size_t)idx[rb + r] : (size_t)(rb + r);
            As[r][kc] = A[ar * lda + kb + kc];
        }
        #pragma unroll
        for (int q = 0; q < 8; ++q) {
            int kr = (tid >> 6) + q * 4, cc = tid & 63;
            Bs[kr][cc] = Bm[(size_t)(kb + kr) * N + nb + cc];
        }
        __syncthreads();
        #pragma unroll
        for (int kk = 0; kk < 32; ++kk) {
            float a0 = As[ty * 2 + 0][kk], a1 = As[ty * 2 + 1][kk];
            float4 b4 = *(const float4*)&Bs[kk][tx * 4];
            acc[0][0] += a0 * b4.x; acc[0][1] += a0 * b4.y; acc[0][2] += a0 * b4.z; acc[0][3] += a0 * b4.w;
            acc[1][0] += a1 * b4.x; acc[1][1] += a1 * b4.y; acc[1][2] += a1 * b4.z; acc[1][3] += a1 * b4.w;
        }
        __syncthreads();
    }
    #pragma unroll
    for (int i = 0; i < 2; ++i) {
        int row = rb + ty * 2 + i;
        #pragma unroll
        for (int j = 0; j < 4; ++j) {
            int col = nb + tx * 4 + j;
            C[(size_t)row * N + col] = fmaxf(acc[i][j] + bias[col], 0.f);
        }
    }
}

// ===== single GEMM + bias + relu (head h2/h3), BM=32/BK=32 =====
__global__ __launch_bounds__(256) void gemm_bias_relu(
    const float* __restrict__ A, int lda,
    const float* __restrict__ Bm, const float* __restrict__ bias,
    float* __restrict__ C, int N, int K)
{
    __shared__ float As[32][33];
    __shared__ float Bs[32][64];
    const int rb = blockIdx.x * 32, nb = blockIdx.y * 64;
    const int tid = threadIdx.x, tx = tid & 15, ty = tid >> 4;
    float acc[2][4] = {};
    for (int kb = 0; kb < K; kb += 32) {
        #pragma unroll
        for (int q = 0; q < 4; ++q) {
            int r = (tid >> 5) + q * 8, kc = tid & 31;
            As[r][kc] = A[(size_t)(rb + r) * lda + kb + kc];
        }
        #pragma unroll
        for (int q = 0; q < 8; ++q) {
            int kr = (tid >> 6) + q * 4, cc = tid & 63;
            Bs[kr][cc] = Bm[(size_t)(kb + kr) * N + nb + cc];
        }
        __syncthreads();
        #pragma unroll
        for (int kk = 0; kk < 32; ++kk) {
            float a0 = As[ty * 2 + 0][kk], a1 = As[ty * 2 + 1][kk];
            float4 b4 = *(const float4*)&Bs[kk][tx * 4];
            acc[0][0] += a0 * b4.x; acc[0][1] += a0 * b4.y; acc[0][2] += a0 * b4.z; acc[0][3] += a0 * b4.w;
            acc[1][0] += a1 * b4.x; acc[1][1] += a1 * b4.y; acc[1][2] += a1 * b4.z; acc[1][3] += a1 * b4.w;
        }
        __syncthreads();
    }
    #pragma unroll
    for (int i = 0; i < 2; ++i) {
        int row = rb + ty * 2 + i;
        #pragma unroll
        for (int j = 0; j < 4; ++j) {
            int col = nb + tx * 4 + j;
            C[(size_t)row * N + col] = fmaxf(acc[i][j] + bias[col], 0.f);
        }
    }
}

// ===== head GEMM1 with fused concat-gather: A[r][k], k in [0,384) from 6 sources =====
__global__ __launch_bounds__(256) void gemm_cat_bias_relu(
    const int* __restrict__ idx_c, const int* __restrict__ idx_p,
    const float* __restrict__ comp_int, const float* __restrict__ Xc,
    const float* __restrict__ fd3, const float* __restrict__ prot_int,
    const float* __restrict__ Xp, const float* __restrict__ fp3,
    const float* __restrict__ Bm, const float* __restrict__ bias,
    float* __restrict__ C, int N)
{
    __shared__ float As[32][33];
    __shared__ float Bs[32][64];
    const int rb = blockIdx.x * 32, nb = blockIdx.y * 64;
    const int tid = threadIdx.x, tx = tid & 15, ty = tid >> 4;
    float acc[2][4] = {};
    for (int kb = 0; kb < 384; kb += 32) {
        const int seg = kb >> 6, off0 = kb & 63;   // uniform per kb (32 | 64)
        #pragma unroll
        for (int q = 0; q < 4; ++q) {
            int r = (tid >> 5) + q * 8, kc = tid & 31;
            int row = rb + r;
            const float* src; size_t ar;
            switch (seg) {
                case 0:  src = comp_int; ar = (size_t)idx_c[row]; break;
                case 1:  src = Xc;       ar = (size_t)idx_c[row]; break;
                case 2:  src = fd3;      ar = (size_t)row;        break;
                case 3:  src = prot_int; ar = (size_t)idx_p[row]; break;
                case 4:  src = Xp;       ar = (size_t)idx_p[row]; break;
                default: src = fp3;      ar = (size_t)row;        break;
            }
            As[r][kc] = src[ar * 64 + off0 + kc];
        }
        #pragma unroll
        for (int q = 0; q < 8; ++q) {
            int kr = (tid >> 6) + q * 4, cc = tid & 63;
            Bs[kr][cc] = Bm[(size_t)(kb + kr) * N + nb + cc];
        }
        __syncthreads();
        #pragma unroll
        for (int kk = 0; kk < 32; ++kk) {
            float a0 = As[ty * 2 + 0][kk], a1 = As[ty * 2 + 1][kk];
            float4 b4 = *(const float4*)&Bs[kk][tx * 4];
            acc[0][0] += a0 * b4.x; acc[0][1] += a0 * b4.y; acc[0][2] += a0 * b4.z; acc[0][3] += a0 * b4.w;
            acc[1][0] += a1 * b4.x; acc[1][1] += a1 * b4.y; acc[1][2] += a1 * b4.z; acc[1][3] += a1 * b4.w;
        }
        __syncthreads();
    }
    #pragma unroll
    for (int i = 0; i < 2; ++i) {
        int row = rb + ty * 2 + i;
        #pragma unroll
        for (int j = 0; j < 4; ++j) {
            int col = nb + tx * 4 + j;
            C[(size_t)row * N + col] = fmaxf(acc[i][j] + bias[col], 0.f);
        }
    }
}

__global__ void head_final(
    const float* __restrict__ h3, const float* __restrict__ W_int,
    const float* __restrict__ b_int, float* __restrict__ out)
{
    int r = blockIdx.x * 256 + threadIdx.x;
    if (r >= BSZ) return;
    float s0 = b_int[0], s1 = b_int[1];
    for (int k = 0; k < 256; ++k) {
        float h = h3[(size_t)r * 256 + k];
        s0 += h * W_int[k * 2 + 0];
        s1 += h * W_int[k * 2 + 1];
    }
    out[r * 2 + 0] = 1.f / (1.f + expf(-s0));
    out[r * 2 + 1] = 1.f / (1.f + expf(-s1));
}

// ======================= launch =======================
extern "C" void kernel_launch(void* const* d_in, const int* in_sizes, int n_in,
                              void* d_out, int out_size, void* d_ws, size_t ws_size,
                              hipStream_t stream)
{
    const int*   idx_c        = (const int*)  d_in[0];
    const int*   idx_p        = (const int*)  d_in[1];
    const int*   compounds    = (const int*)  d_in[2];
    const int*   proteins     = (const int*)  d_in[3];
    const float* adjacencies  = (const float*)d_in[4];
    const float* A_c          = (const float*)d_in[5];
    const float* A_p          = (const float*)d_in[6];
    const float* embed_fp     = (const float*)d_in[7];
    const float* embed_word   = (const float*)d_in[8];
    const float* Xs_c         = (const float*)d_in[9];
    const float* Xs_p         = (const float*)d_in[10];
    const float* drug_feat    = (const float*)d_in[11];
    const float* protein_feat = (const float*)d_in[12];
    const float* W_gnn        = (const float*)d_in[13];
    const float* b_gnn        = (const float*)d_in[14];
    const float* K_cnn        = (const float*)d_in[15];
    const float* b_cnn        = (const float*)d_in[16];
    const float* W_gcn_d      = (const float*)d_in[17];
    const float* b_gcn_d      = (const float*)d_in[18];
    const float* W_gcn_p      = (const float*)d_in[19];
    const float* b_gcn_p      = (const float*)d_in[20];
    const float* Wd1 = (const float*)d_in[21]; const float* bd1 = (const float*)d_in[22];
    const float* Wd2 = (const float*)d_in[23]; const float* bd2 = (const float*)d_in[24];
    const float* Wd3 = (const float*)d_in[25]; const float* bd3 = (const float*)d_in[26];
    const float* Wp1 = (const float*)d_in[27]; const float* bp1 = (const float*)d_in[28];
    const float* Wp2 = (const float*)d_in[29]; const float* bp2 = (const float*)d_in[30];
    const float* Wp3 = (const float*)d_in[31]; const float* bp3 = (const float*)d_in[32];
    const float* Wo1 = (const float*)d_in[33]; const float* bo1 = (const float*)d_in[34];
    const float* Wo2 = (const float*)d_in[35]; const float* bo2 = (const float*)d_in[36];
    const float* Wo3 = (const float*)d_in[37]; const float* bo3 = (const float*)d_in[38];
    const float* W_int = (const float*)d_in[39]; const float* b_int = (const float*)d_in[40];

    float* ws = (float*)d_ws;
    float* comp_int  = ws; ws += NC * 64;
    float* prot_part = ws; ws += NP * 16 * 64;
    float* prot_int  = ws; ws += NP * 64;
    float* wtab_g    = ws; ws += 8448;          // 3*11*512 halves
    float* ehp_g     = ws; ws += NW * 40;       // 8000 x 80 halves
    float* part_c    = ws; ws += 8 * NC * 64;
    float* part_p    = ws; ws += 8 * NP * 64;
    float* Xc_a = ws; ws += NC * 64;
    float* Xc_b = ws; ws += NC * 64;
    float* Xp_a = ws; ws += NP * 64;
    float* Xp_b = ws; ws += NP * 64;
    float* fd1 = ws; ws += BSZ * 128;
    float* fd2 = ws; ws += BSZ * 64;
    float* fd3 = ws; ws += BSZ * 64;
    float* fp1 = ws; ws += BSZ * 128;
    float* fp2 = ws; ws += BSZ * 64;
    float* fp3 = ws; ws += BSZ * 64;
    float* h1  = ws; ws += BSZ * 256;
    float* h2m = ws; ws += BSZ * 256;
    float* h3  = ws; ws += BSZ * 256;
    (void)ws_size; (void)in_sizes; (void)n_in; (void)out_size;

    // one-time prep: band-weight table + padded fp16 embedding (fused)
    cnn_prep<<<(16896 + NW * 80 + 255) / 256, 256, 0, stream>>>(
        K_cnn, (_Float16*)wtab_g, embed_word, (_Float16*)ehp_g);
    // branch 1: compound GNN
    gnn_kernel<<<NC, 320, 0, stream>>>(compounds, adjacencies, embed_fp, W_gnn, b_gnn, comp_int);
    // branch 2: protein CNN (banded MFMA)
    cnn_kernel<<<dim3(16, NP), 256, 0, stream>>>(proteins, (const _Float16*)ehp_g, (const half8_t*)wtab_g, b_cnn, prot_part);
    cnn_reduce<<<NP, 64, 0, stream>>>(prot_part, prot_int);
    // branch 3: GCN drug+protein fused per stage
    spk_gemm64_dual<<<dim3(32, 8, 2), 256, 0, stream>>>(
        A_c, Xs_c, part_c, NC, 256, A_p, Xs_p, part_p, NP, 192, 24);
    gcn_epi_dual<<<dim3(32, 1, 2), 256, 0, stream>>>(
        part_c, NC, W_gcn_d, b_gcn_d, Xc_a, part_p, NP, W_gcn_p, b_gcn_p, Xp_a, 24);
    spk_gemm64_dual<<<dim3(32, 8, 2), 256, 0, stream>>>(
        A_c, Xc_a, part_c, NC, 256, A_p, Xp_a, part_p, NP, 192, 24);
    gcn_epi_dual<<<dim3(32, 1, 2), 256, 0, stream>>>(
        part_c, NC, W_gcn_d + 4096, b_gcn_d + 64, Xc_b,
        part_p, NP, W_gcn_p + 4096, b_gcn_p + 64, Xp_b, 24);
    // branches 4+5: drug & protein MLPs fused per layer
    gemm_br_dual<true ><<<dim3(128, 2, 2), 256, 0, stream>>>(
        drug_feat, idx_c, Wd1, bd1, fd1, protein_feat, idx_p, Wp1, bp1, fp1, 1024, 128, 1024);
    gemm_br_dual<false><<<dim3(128, 1, 2), 256, 0, stream>>>(
        fd1, nullptr, Wd2, bd2, fd2, fp1, nullptr, Wp2, bp2, fp2, 128, 64, 128);
    gemm_br_dual<false><<<dim3(128, 1, 2), 256, 0, stream>>>(
        fd2, nullptr, Wd3, bd3, fd3, fp2, nullptr, Wp3, bp3, fp3, 64, 64, 64);
    // head: concat fused into first GEMM
    gemm_cat_bias_relu<<<dim3(128, 4), 256, 0, stream>>>(
        idx_c, idx_p, comp_int, Xc_b, fd3, prot_int, Xp_b, fp3, Wo1, bo1, h1, 256);
    gemm_bias_relu<<<dim3(128, 4), 256, 0, stream>>>(h1, 256, Wo2, bo2, h2m, 256, 256);
    gemm_bias_relu<<<dim3(128, 4), 256, 0, stream>>>(h2m, 256, Wo3, bo3, h3, 256, 256);
    head_final<<<(BSZ + 255) / 256, 256, 0, stream>>>(h3, W_int, b_int, (float*)d_out);
}